// Round 3
// baseline (54456.488 us; speedup 1.0000x reference)
//
#include <hip/hip_runtime.h>
#include <math.h>

#define B_  50
#define T_  512
#define I_  1024
#define H_  512
#define NG_ 2048
#define BP  64   // padded batch rows in h buffers
#define NBLK 256 // persistent scan grid size (== CU count; all co-resident)

__device__ __forceinline__ float sigmf(float x) {
    return 1.0f / (1.0f + __expf(-x));
}
// overflow-safe tanh via e^{-2|x|} in (0,1]
__device__ __forceinline__ float tanh_fast(float x) {
    float ax = fabsf(x);
    float e  = __expf(-2.0f * ax);
    float t  = (1.0f - e) / (1.0f + e);
    return copysignf(t, x);
}

// ---------------------------------------------------------------------------
// C[m][n] = bias[n] + sum_k A[m][k] * W[n][k]
// 128x128 tile, K-step 16, 256 threads, 8x8 accum per thread.
// ---------------------------------------------------------------------------
__global__ __launch_bounds__(256) void gemm_bias(
    const float* __restrict__ A, const float* __restrict__ W,
    const float* __restrict__ bias, float* __restrict__ C,
    int M, int N, int K) {
    __shared__ float As[16][132];
    __shared__ float Ws[16][132];
    const int tid = threadIdx.x;
    const int m0 = blockIdx.y * 128, n0 = blockIdx.x * 128;
    const int lr = tid >> 2;
    const int lk = (tid & 3) << 2;
    const int tx = tid & 15, ty = tid >> 4;

    float acc[8][8];
#pragma unroll
    for (int i = 0; i < 8; ++i)
#pragma unroll
        for (int j = 0; j < 8; ++j) acc[i][j] = 0.0f;

    for (int k0 = 0; k0 < K; k0 += 16) {
        float4 a0 = *(const float4*)(A + (size_t)(m0 + lr) * K + k0 + lk);
        float4 a1 = *(const float4*)(A + (size_t)(m0 + lr + 64) * K + k0 + lk);
        float4 w0 = *(const float4*)(W + (size_t)(n0 + lr) * K + k0 + lk);
        float4 w1 = *(const float4*)(W + (size_t)(n0 + lr + 64) * K + k0 + lk);
        __syncthreads();
        As[lk + 0][lr] = a0.x; As[lk + 1][lr] = a0.y; As[lk + 2][lr] = a0.z; As[lk + 3][lr] = a0.w;
        As[lk + 0][lr + 64] = a1.x; As[lk + 1][lr + 64] = a1.y; As[lk + 2][lr + 64] = a1.z; As[lk + 3][lr + 64] = a1.w;
        Ws[lk + 0][lr] = w0.x; Ws[lk + 1][lr] = w0.y; Ws[lk + 2][lr] = w0.z; Ws[lk + 3][lr] = w0.w;
        Ws[lk + 0][lr + 64] = w1.x; Ws[lk + 1][lr + 64] = w1.y; Ws[lk + 2][lr + 64] = w1.z; Ws[lk + 3][lr + 64] = w1.w;
        __syncthreads();
#pragma unroll
        for (int k = 0; k < 16; ++k) {
            const float4 av0 = *(const float4*)&As[k][tx * 4];
            const float4 av1 = *(const float4*)&As[k][64 + tx * 4];
            const float4 bv0 = *(const float4*)&Ws[k][ty * 4];
            const float4 bv1 = *(const float4*)&Ws[k][64 + ty * 4];
            float a[8] = {av0.x, av0.y, av0.z, av0.w, av1.x, av1.y, av1.z, av1.w};
            float b[8] = {bv0.x, bv0.y, bv0.z, bv0.w, bv1.x, bv1.y, bv1.z, bv1.w};
#pragma unroll
            for (int i = 0; i < 8; ++i)
#pragma unroll
                for (int j = 0; j < 8; ++j) acc[i][j] = fmaf(a[i], b[j], acc[i][j]);
        }
    }

    const float4 bv0 = *(const float4*)&bias[n0 + ty * 4];
    const float4 bv1 = *(const float4*)&bias[n0 + 64 + ty * 4];
    const float bb[8] = {bv0.x, bv0.y, bv0.z, bv0.w, bv1.x, bv1.y, bv1.z, bv1.w};
#pragma unroll
    for (int i = 0; i < 8; ++i) {
        int m = m0 + ((i < 4) ? (tx * 4 + i) : (64 + tx * 4 + (i - 4)));
        float4 v0, v1;
        v0.x = acc[i][0] + bb[0]; v0.y = acc[i][1] + bb[1];
        v0.z = acc[i][2] + bb[2]; v0.w = acc[i][3] + bb[3];
        v1.x = acc[i][4] + bb[4]; v1.y = acc[i][5] + bb[5];
        v1.z = acc[i][6] + bb[6]; v1.w = acc[i][7] + bb[7];
        *(float4*)&C[(size_t)m * N + n0 + ty * 4] = v0;
        *(float4*)&C[(size_t)m * N + n0 + 64 + ty * 4] = v1;
    }
}

// ---------------------------------------------------------------------------
// hTa[b][j] = h0[b][j] (b<50 else 0); hTb zeroed (pad rows must be finite)
// ---------------------------------------------------------------------------
__global__ void init_state(const float* __restrict__ h0,
                           float* __restrict__ hTa, float* __restrict__ hTb) {
    int idx = blockIdx.x * blockDim.x + threadIdx.x;
    if (idx >= BP * H_) return;
    int b = idx >> 9;
    int j = idx & (H_ - 1);
    hTa[idx] = (b < B_) ? h0[b * H_ + j] : 0.0f;
    hTb[idx] = 0.0f;
}

// ---------------------------------------------------------------------------
// Persistent LSTM scan. 256 blocks; block bi owns h-components j0=2*bi,j0+1
// (8 gate rows). W_hh slice in LDS once; c in LDS for the whole scan.
// Grid sync per step via contention-free per-block epoch flags:
//   - each block release-stores flags[bid*32] = t+1 (own 128B line, no RMW)
//   - wave 0 polls all 256 flags (4 per-lane acquire loads + __all)
//   - agent acquire fence, then __syncthreads releases the block.
// h double-buffered; step-t readers of buffer A are all done before any
// block starts step t+1 writes to A (flag t+1 implies compute t finished).
// ---------------------------------------------------------------------------
__global__ __launch_bounds__(256, 1) void lstm_scan(
    const float* __restrict__ xg,     // [B][T][NG], bias already included
    float* __restrict__ hTa,          // [BP][H] input at even t
    float* __restrict__ hTb,          // [BP][H] input at odd t
    const float* __restrict__ c0,     // [B][H] initial cell state (this layer)
    const float* __restrict__ W_hh,   // [NG][H]
    float* __restrict__ hs,           // [B][T][H] or nullptr
    int* __restrict__ flags) {        // NBLK*32 ints, zeroed
    __shared__ float w_lds[8][H_];    // 16 KB
    __shared__ float g_lds[8][BP];    // 2 KB
    __shared__ float c_lds[2][BP];    // 0.5 KB
    const int tid = threadIdx.x;
    const int bid = blockIdx.x;
    const int j0 = bid * 2;

    // stage 8 W_hh rows -> LDS once (coalesced float4)
#pragma unroll
    for (int it = 0; it < 4; ++it) {
        int idx = tid + it * 256;
        int rr = idx >> 7;
        int kk = (idx & 127) << 2;
        int row = (rr >> 1) * H_ + j0 + (rr & 1);
        *(float4*)&w_lds[rr][kk] = *(const float4*)&W_hh[(size_t)row * H_ + kk];
    }
    // stage initial c -> LDS (block-private for whole scan)
    if (tid < 128) {
        int jj = tid >> 6, b = tid & 63;
        c_lds[jj][b] = (b < B_) ? c0[(size_t)b * H_ + j0 + jj] : 0.0f;
    }
    __syncthreads();

    const int bl = tid & 31;    // batch lane 0..31
    const int r  = tid >> 5;    // gate-row slot 0..7
    const int row = (r >> 1) * H_ + j0 + (r & 1);
    const bool has1 = (bl + 32 < B_);
    const float* xg_p0 = xg + (size_t)bl * T_ * NG_ + row;
    const float* xg_p1 = xg + (size_t)(bl + 32) * T_ * NG_ + row;
    float x0 = xg_p0[0];
    float x1 = has1 ? xg_p1[0] : 0.0f;

    const int jj2 = tid >> 6;   // writer decomposition (tid<128)
    const int wb  = tid & 63;
    const int wj  = j0 + jj2;

    int* myflag = flags + bid * 32;

    for (int t = 0; t < T_; ++t) {
        const float* hin  = (t & 1) ? hTb : hTa;
        float*       hout = (t & 1) ? hTa : hTb;

        const float* hb0 = hin + (size_t)bl * H_;
        const float* hb1 = hin + (size_t)(bl + 32) * H_;
        float acc0 = 0.0f, acc1 = 0.0f;
#pragma unroll 4
        for (int k = 0; k < H_; k += 4) {
            const float4 w4 = *(const float4*)&w_lds[r][k];
            const float4 ha = *(const float4*)&hb0[k];
            const float4 hb = *(const float4*)&hb1[k];
            acc0 = fmaf(w4.x, ha.x, acc0); acc1 = fmaf(w4.x, hb.x, acc1);
            acc0 = fmaf(w4.y, ha.y, acc0); acc1 = fmaf(w4.y, hb.y, acc1);
            acc0 = fmaf(w4.z, ha.z, acc0); acc1 = fmaf(w4.z, hb.z, acc1);
            acc0 = fmaf(w4.w, ha.w, acc0); acc1 = fmaf(w4.w, hb.w, acc1);
        }
        g_lds[r][bl]      = acc0 + x0;
        g_lds[r][bl + 32] = acc1 + x1;

        // cross-step prefetch of xg (read-only; overlaps with barrier)
        if (t + 1 < T_) {
            x0 = xg_p0[(size_t)(t + 1) * NG_];
            x1 = has1 ? xg_p1[(size_t)(t + 1) * NG_] : 0.0f;
        }
        __syncthreads();

        if (tid < 128 && wb < B_) {
            float iv = g_lds[0 + jj2][wb];
            float fv = g_lds[2 + jj2][wb];
            float gv = g_lds[4 + jj2][wb];
            float ov = g_lds[6 + jj2][wb];
            float cn = sigmf(fv) * c_lds[jj2][wb] + sigmf(iv) * tanh_fast(gv);
            float hn = sigmf(ov) * tanh_fast(cn);
            c_lds[jj2][wb] = cn;
            hout[(size_t)wb * H_ + wj] = hn;
            if (hs) hs[((size_t)wb * T_ + t) * H_ + wj] = hn;
        }
        // all waves drain stores (s_waitcnt vmcnt(0) precedes s_barrier)
        __syncthreads();

        // publish: own line, no contention
        if (tid == 0)
            __hip_atomic_store(myflag, t + 1, __ATOMIC_RELEASE, __HIP_MEMORY_SCOPE_AGENT);
        // wave 0 polls all 256 flags
        if (tid < 64) {
            const int target = t + 1;
            for (;;) {
                int v0 = __hip_atomic_load(flags + (size_t)(tid)       * 32, __ATOMIC_ACQUIRE, __HIP_MEMORY_SCOPE_AGENT);
                int v1 = __hip_atomic_load(flags + (size_t)(tid + 64)  * 32, __ATOMIC_ACQUIRE, __HIP_MEMORY_SCOPE_AGENT);
                int v2 = __hip_atomic_load(flags + (size_t)(tid + 128) * 32, __ATOMIC_ACQUIRE, __HIP_MEMORY_SCOPE_AGENT);
                int v3 = __hip_atomic_load(flags + (size_t)(tid + 192) * 32, __ATOMIC_ACQUIRE, __HIP_MEMORY_SCOPE_AGENT);
                bool ok = (v0 >= target) & (v1 >= target) & (v2 >= target) & (v3 >= target);
                if (__all(ok)) break;
                __builtin_amdgcn_s_sleep(1);
            }
            __builtin_amdgcn_fence(__ATOMIC_ACQUIRE, "agent");
        }
        __syncthreads();
    }
}

// ---------------------------------------------------------------------------
// head: out[b][o] = lin2_b[o] + sum_u tanh(lin1_b[u]+sum_j h[b][j] lin1_W[u][j]) lin2_W[o][u]
// ---------------------------------------------------------------------------
__global__ __launch_bounds__(512) void head(
    const float* __restrict__ hT, const float* __restrict__ lin1_W,
    const float* __restrict__ lin1_b, const float* __restrict__ lin2_W,
    const float* __restrict__ lin2_b, float* __restrict__ out) {
    __shared__ float zs[B_][10];
    int tid = threadIdx.x;
    if (tid < B_ * 10) {
        int b = tid / 10, u = tid % 10;
        float acc = lin1_b[u];
        for (int j = 0; j < H_; ++j)
            acc = fmaf(hT[(size_t)b * H_ + j], lin1_W[u * H_ + j], acc);
        zs[b][u] = tanh_fast(acc);
    }
    __syncthreads();
    if (tid < B_ * 2) {
        int b = tid >> 1, o = tid & 1;
        float acc = lin2_b[o];
#pragma unroll
        for (int u = 0; u < 10; ++u)
            acc = fmaf(zs[b][u], lin2_W[o * 10 + u], acc);
        out[b * 2 + o] = acc;
    }
}

// ---------------------------------------------------------------------------
extern "C" void kernel_launch(void* const* d_in, const int* in_sizes, int n_in,
                              void* d_out, int out_size, void* d_ws, size_t ws_size,
                              hipStream_t stream) {
    const float* input  = (const float*)d_in[0];
    const float* pca_W  = (const float*)d_in[1];
    const float* pca_b  = (const float*)d_in[2];
    const float* W_ih0  = (const float*)d_in[3];
    const float* W_hh0  = (const float*)d_in[4];
    const float* b0     = (const float*)d_in[5];
    const float* W_ih1  = (const float*)d_in[6];
    const float* W_hh1  = (const float*)d_in[7];
    const float* b1     = (const float*)d_in[8];
    const float* h0     = (const float*)d_in[9];
    const float* c0     = (const float*)d_in[10];
    const float* lin1_W = (const float*)d_in[11];
    const float* lin1_b = (const float*)d_in[12];
    const float* lin2_W = (const float*)d_in[13];
    const float* lin2_b = (const float*)d_in[14];
    float* out = (float*)d_out;

    float* ws = (float*)d_ws;
    size_t off = 0;
    float* xg   = ws + off; off += (size_t)B_ * T_ * NG_;  // 52.4M floats
    float* xbuf = ws + off; off += (size_t)B_ * T_ * H_;   // 13.1M floats
    float* hs0  = xbuf;                                    // alias: xbuf dead before hs0 born
    float* hT0  = ws + off; off += BP * H_;
    float* hT1  = ws + off; off += BP * H_;
    int*   flg0 = (int*)(ws + off); off += NBLK * 32;      // layer-0 flags
    int*   flg1 = (int*)(ws + off); off += NBLK * 32;      // layer-1 flags

    const int M = B_ * T_;  // 25600

    // zero both flag arrays (ws is re-poisoned 0xAA before every timed launch;
    // 0xAAAAAAAA is negative as int -> poll would never terminate)
    hipMemsetAsync(flg0, 0, 2 * NBLK * 32 * sizeof(int), stream);

    // 1. pca: xbuf = input @ pca_W^T + pca_b   (M x 512, K=1024)
    {
        dim3 g(H_ / 128, M / 128);
        gemm_bias<<<g, 256, 0, stream>>>(input, pca_W, pca_b, xbuf, M, H_, I_);
    }
    // 2. xg0 = xbuf @ W_ih0^T + b0             (M x 2048, K=512)
    {
        dim3 g(NG_ / 128, M / 128);
        gemm_bias<<<g, 256, 0, stream>>>(xbuf, W_ih0, b0, xg, M, NG_, H_);
    }
    // 3. layer-0 scan (persistent; writes hs0)
    init_state<<<(BP * H_) / 256, 256, 0, stream>>>(h0, hT0, hT1);
    lstm_scan<<<NBLK, 256, 0, stream>>>(xg, hT0, hT1, c0, W_hh0, hs0, flg0);
    // 4. xg1 = hs0 @ W_ih1^T + b1
    {
        dim3 g(NG_ / 128, M / 128);
        gemm_bias<<<g, 256, 0, stream>>>(hs0, W_ih1, b1, xg, M, NG_, H_);
    }
    // 5. layer-1 scan (no hs store; final h lands in hT0 since T even)
    init_state<<<(BP * H_) / 256, 256, 0, stream>>>(h0 + B_ * H_, hT0, hT1);
    lstm_scan<<<NBLK, 256, 0, stream>>>(xg, hT0, hT1, c0 + B_ * H_, W_hh1, nullptr, flg1);
    // 6. head
    head<<<1, 512, 0, stream>>>(hT0, lin1_W, lin1_b, lin2_W, lin2_b, out);
}

// Round 4
// 32876.755 us; speedup vs baseline: 1.6564x; 1.6564x over previous
//
#include <hip/hip_runtime.h>
#include <math.h>

#define B_  50
#define T_  512
#define I_  1024
#define H_  512
#define NG_ 2048
#define BP  64    // padded batch columns in transposed h buffers
#define NBLK 256  // persistent scan grid (== CU count; co-resident)
#define FLS 32    // flag stride in ints (128 B line each)

__device__ __forceinline__ float sigmf(float x) {
    return 1.0f / (1.0f + __expf(-x));
}
// overflow-safe tanh via e^{-2|x|} in (0,1]
__device__ __forceinline__ float tanh_fast(float x) {
    float ax = fabsf(x);
    float e  = __expf(-2.0f * ax);
    float t  = (1.0f - e) / (1.0f + e);
    return copysignf(t, x);
}

// ---------------------------------------------------------------------------
// C[m][n] = bias[n] + sum_k A[m][k] * W[n][k]
// 128x128 tile, K-step 16, 256 threads, 8x8 accum per thread.
// ---------------------------------------------------------------------------
__global__ __launch_bounds__(256) void gemm_bias(
    const float* __restrict__ A, const float* __restrict__ W,
    const float* __restrict__ bias, float* __restrict__ C,
    int M, int N, int K) {
    __shared__ float As[16][132];
    __shared__ float Ws[16][132];
    const int tid = threadIdx.x;
    const int m0 = blockIdx.y * 128, n0 = blockIdx.x * 128;
    const int lr = tid >> 2;
    const int lk = (tid & 3) << 2;
    const int tx = tid & 15, ty = tid >> 4;

    float acc[8][8];
#pragma unroll
    for (int i = 0; i < 8; ++i)
#pragma unroll
        for (int j = 0; j < 8; ++j) acc[i][j] = 0.0f;

    for (int k0 = 0; k0 < K; k0 += 16) {
        float4 a0 = *(const float4*)(A + (size_t)(m0 + lr) * K + k0 + lk);
        float4 a1 = *(const float4*)(A + (size_t)(m0 + lr + 64) * K + k0 + lk);
        float4 w0 = *(const float4*)(W + (size_t)(n0 + lr) * K + k0 + lk);
        float4 w1 = *(const float4*)(W + (size_t)(n0 + lr + 64) * K + k0 + lk);
        __syncthreads();
        As[lk + 0][lr] = a0.x; As[lk + 1][lr] = a0.y; As[lk + 2][lr] = a0.z; As[lk + 3][lr] = a0.w;
        As[lk + 0][lr + 64] = a1.x; As[lk + 1][lr + 64] = a1.y; As[lk + 2][lr + 64] = a1.z; As[lk + 3][lr + 64] = a1.w;
        Ws[lk + 0][lr] = w0.x; Ws[lk + 1][lr] = w0.y; Ws[lk + 2][lr] = w0.z; Ws[lk + 3][lr] = w0.w;
        Ws[lk + 0][lr + 64] = w1.x; Ws[lk + 1][lr + 64] = w1.y; Ws[lk + 2][lr + 64] = w1.z; Ws[lk + 3][lr + 64] = w1.w;
        __syncthreads();
#pragma unroll
        for (int k = 0; k < 16; ++k) {
            const float4 av0 = *(const float4*)&As[k][tx * 4];
            const float4 av1 = *(const float4*)&As[k][64 + tx * 4];
            const float4 bv0 = *(const float4*)&Ws[k][ty * 4];
            const float4 bv1 = *(const float4*)&Ws[k][64 + ty * 4];
            float a[8] = {av0.x, av0.y, av0.z, av0.w, av1.x, av1.y, av1.z, av1.w};
            float b[8] = {bv0.x, bv0.y, bv0.z, bv0.w, bv1.x, bv1.y, bv1.z, bv1.w};
#pragma unroll
            for (int i = 0; i < 8; ++i)
#pragma unroll
                for (int j = 0; j < 8; ++j) acc[i][j] = fmaf(a[i], b[j], acc[i][j]);
        }
    }

    const float4 bv0 = *(const float4*)&bias[n0 + ty * 4];
    const float4 bv1 = *(const float4*)&bias[n0 + 64 + ty * 4];
    const float bb[8] = {bv0.x, bv0.y, bv0.z, bv0.w, bv1.x, bv1.y, bv1.z, bv1.w};
#pragma unroll
    for (int i = 0; i < 8; ++i) {
        int m = m0 + ((i < 4) ? (tx * 4 + i) : (64 + tx * 4 + (i - 4)));
        float4 v0, v1;
        v0.x = acc[i][0] + bb[0]; v0.y = acc[i][1] + bb[1];
        v0.z = acc[i][2] + bb[2]; v0.w = acc[i][3] + bb[3];
        v1.x = acc[i][4] + bb[4]; v1.y = acc[i][5] + bb[5];
        v1.z = acc[i][6] + bb[6]; v1.w = acc[i][7] + bb[7];
        *(float4*)&C[(size_t)m * N + n0 + ty * 4] = v0;
        *(float4*)&C[(size_t)m * N + n0 + 64 + ty * 4] = v1;
    }
}

// ---------------------------------------------------------------------------
// hTa[j][b] = h0[b][j] (b<50 else 0); hTb fully zeroed (pads stay 0 forever)
// ---------------------------------------------------------------------------
__global__ void init_state(const float* __restrict__ h0,
                           float* __restrict__ hTa, float* __restrict__ hTb) {
    int idx = blockIdx.x * blockDim.x + threadIdx.x;
    if (idx >= H_ * BP) return;
    int j = idx >> 6, b = idx & 63;
    hTa[idx] = (b < B_) ? h0[b * H_ + j] : 0.0f;
    hTb[idx] = 0.0f;
}

// ---------------------------------------------------------------------------
// wt[bid][k][r] = W_hh[(r>>1)*512 + bid*2 + (r&1)][k]
// Per-scan-block W slice, k-major so (k,r) reads in the scan are a single
// wave-uniform contiguous 8-float chunk -> scalar (SMEM) loads.
// ---------------------------------------------------------------------------
__global__ __launch_bounds__(256) void w_transpose(
    const float* __restrict__ W, float* __restrict__ wt) {
    const int bid = blockIdx.x, tid = threadIdx.x;
    const int j0 = bid * 2;
    float* o = wt + (size_t)bid * 512 * 8;
#pragma unroll
    for (int r = 0; r < 8; ++r) {
        int row = (r >> 1) * H_ + j0 + (r & 1);
        const float* src = W + (size_t)row * H_;
        o[(size_t)tid * 8 + r]         = src[tid];
        o[(size_t)(tid + 256) * 8 + r] = src[tid + 256];
    }
}

// ---------------------------------------------------------------------------
// Persistent LSTM scan. 256 blocks x 256 threads; block bi owns h-components
// j0=2*bi, j0+1 (8 gate rows). Per step:
//   stage: hin (128 KB, [k][64]) -> LDS, 32 independent float4/thread
//   phase1: split-k matvec — thread (b=tid&63, kc=tid>>6) accumulates 8 gate
//           rows over its 128-k chunk; W from read-only wt via uniform
//           (scalar-pipe) loads; h from LDS (2-way, free)
//   phase3: 4-way reduce via LDS + add xg
//   phase4: gate nonlinearity, c in LDS, write hout (+hs)
//   barrier: 2-level flag tree — members store own line; 8 leaders poll 32
//            member flags each; everyone polls 8 lead flags. No RMW, minimal
//            cross-XCD line traffic.
// ---------------------------------------------------------------------------
__global__ __launch_bounds__(256, 1) void lstm_scan(
    const float* __restrict__ xg,     // [B][T][NG], bias included
    float* __restrict__ hTa,          // [H][BP] input at even t
    float* __restrict__ hTb,          // [H][BP] input at odd t
    const float* __restrict__ c0,     // [B][H] initial cell state
    const float* __restrict__ wt,     // [NBLK][512][8] pre-transposed W_hh
    float* __restrict__ hs,           // [B][T][H] or nullptr
    int* __restrict__ mflag,          // NBLK*FLS ints, zeroed
    int* __restrict__ lflag) {        // 8*FLS ints, zeroed
    __shared__ float h_lds[H_ * BP];  // 128 KB
    __shared__ float red[4][8][BP];   // 8 KB
    __shared__ float g_lds[8][BP];    // 2 KB
    __shared__ float c_lds[2][BP];    // 0.5 KB
    const int tid = threadIdx.x;
    const int bid = blockIdx.x;
    const int j0 = bid * 2;
    const int b  = tid & 63;
    const int kc = tid >> 6;
    const float* wts = wt + (size_t)bid * 512 * 8;

    if (tid < 128) {
        int jj = tid >> 6, bb = tid & 63;
        c_lds[jj][bb] = (bb < B_) ? c0[(size_t)bb * H_ + j0 + jj] : 0.0f;
    }

    // phase-3 output pair: (r1, b) and (r2, b)
    const int r1 = tid >> 6;          // 0..3
    const int r2 = r1 + 4;            // 4..7
    const int row1 = (r1 >> 1) * H_ + j0 + (r1 & 1);
    const int row2 = (r2 >> 1) * H_ + j0 + (r2 & 1);
    const bool bok = (b < B_);
    const float* xp1 = xg + (size_t)b * T_ * NG_ + row1;
    const float* xp2 = xg + (size_t)b * T_ * NG_ + row2;
    float x1 = bok ? xp1[0] : 0.0f;
    float x2 = bok ? xp2[0] : 0.0f;

    const int wjj = tid >> 6;         // writer decomposition (tid<128)
    const int wb  = tid & 63;

    for (int t = 0; t < T_; ++t) {
        const float* hin  = (t & 1) ? hTb : hTa;
        float*       hout = (t & 1) ? hTa : hTb;

        // ---- stage hin -> LDS (32 independent float4 per thread) ----
        {
            const float4* src = (const float4*)hin;
            float4* dst = (float4*)h_lds;
#pragma unroll 8
            for (int i = tid; i < (H_ * BP) / 4; i += 256) dst[i] = src[i];
        }
        __syncthreads();

        // ---- phase 1: partial dots over this thread's 128-k chunk ----
        float a0 = 0, a1 = 0, a2 = 0, a3 = 0, a4 = 0, a5 = 0, a6 = 0, a7 = 0;
        {
            const float* hck = h_lds + kc * 128 * BP + b;
            const float* wp  = wts + (size_t)kc * 128 * 8;
#pragma unroll 4
            for (int k = 0; k < 128; ++k) {
                float hv = hck[k * BP];
                const float4 wa = *(const float4*)(wp + (k << 3));
                const float4 wb4 = *(const float4*)(wp + (k << 3) + 4);
                a0 = fmaf(wa.x,  hv, a0); a1 = fmaf(wa.y,  hv, a1);
                a2 = fmaf(wa.z,  hv, a2); a3 = fmaf(wa.w,  hv, a3);
                a4 = fmaf(wb4.x, hv, a4); a5 = fmaf(wb4.y, hv, a5);
                a6 = fmaf(wb4.z, hv, a6); a7 = fmaf(wb4.w, hv, a7);
            }
        }
        red[kc][0][b] = a0; red[kc][1][b] = a1; red[kc][2][b] = a2; red[kc][3][b] = a3;
        red[kc][4][b] = a4; red[kc][5][b] = a5; red[kc][6][b] = a6; red[kc][7][b] = a7;
        __syncthreads();

        // ---- phase 3: reduce partials + xg -> g_lds ----
        float s1 = red[0][r1][b] + red[1][r1][b] + red[2][r1][b] + red[3][r1][b] + x1;
        float s2 = red[0][r2][b] + red[1][r2][b] + red[2][r2][b] + red[3][r2][b] + x2;
        g_lds[r1][b] = s1;
        g_lds[r2][b] = s2;
        // prefetch next step's xg (consumed after the barrier)
        if (t + 1 < T_) {
            x1 = bok ? xp1[(size_t)(t + 1) * NG_] : 0.0f;
            x2 = bok ? xp2[(size_t)(t + 1) * NG_] : 0.0f;
        }
        __syncthreads();

        // ---- phase 4: gate update ----
        if (tid < 128 && wb < B_) {
            float iv = g_lds[0 + wjj][wb];
            float fv = g_lds[2 + wjj][wb];
            float gv = g_lds[4 + wjj][wb];
            float ov = g_lds[6 + wjj][wb];
            float cn = sigmf(fv) * c_lds[wjj][wb] + sigmf(iv) * tanh_fast(gv);
            float hn = sigmf(ov) * tanh_fast(cn);
            c_lds[wjj][wb] = cn;
            hout[(j0 + wjj) * BP + wb] = hn;
            if (hs) hs[((size_t)wb * T_ + t) * H_ + j0 + wjj] = hn;
        }
        __syncthreads();   // all waves' stores drained (vmcnt0 before s_barrier)

        // ---- 2-level flag-tree grid barrier ----
        if (tid == 0)
            __hip_atomic_store(mflag + (size_t)bid * FLS, t + 1,
                               __ATOMIC_RELEASE, __HIP_MEMORY_SCOPE_AGENT);
        if (bid < 8 && tid < 64) {
            // leader of group `bid`: members are bids ≡ bid (mod 8)
            const int tgt = t + 1;
            const int* f = mflag + (size_t)(bid + (tid & 31) * 8) * FLS;
            for (;;) {
                int v = (tid < 32)
                    ? __hip_atomic_load(f, __ATOMIC_ACQUIRE, __HIP_MEMORY_SCOPE_AGENT)
                    : tgt;
                if (__all(v >= tgt)) break;
                __builtin_amdgcn_s_sleep(1);
            }
            if (tid == 0)
                __hip_atomic_store(lflag + (size_t)bid * FLS, tgt,
                                   __ATOMIC_RELEASE, __HIP_MEMORY_SCOPE_AGENT);
        }
        if (tid < 64) {
            const int tgt = t + 1;
            const int* f = lflag + (size_t)(tid & 7) * FLS;
            for (;;) {
                int v = (tid < 8)
                    ? __hip_atomic_load(f, __ATOMIC_ACQUIRE, __HIP_MEMORY_SCOPE_AGENT)
                    : tgt;
                if (__all(v >= tgt)) break;
                __builtin_amdgcn_s_sleep(1);
            }
            __builtin_amdgcn_fence(__ATOMIC_ACQUIRE, "agent");
        }
        __syncthreads();
    }
}

// ---------------------------------------------------------------------------
// head (hT transposed [H][BP])
// ---------------------------------------------------------------------------
__global__ __launch_bounds__(512) void head(
    const float* __restrict__ hT, const float* __restrict__ lin1_W,
    const float* __restrict__ lin1_b, const float* __restrict__ lin2_W,
    const float* __restrict__ lin2_b, float* __restrict__ out) {
    __shared__ float zs[B_][10];
    int tid = threadIdx.x;
    if (tid < B_ * 10) {
        int b = tid / 10, u = tid % 10;
        float acc = lin1_b[u];
        for (int j = 0; j < H_; ++j)
            acc = fmaf(hT[j * BP + b], lin1_W[u * H_ + j], acc);
        zs[b][u] = tanh_fast(acc);
    }
    __syncthreads();
    if (tid < B_ * 2) {
        int b = tid >> 1, o = tid & 1;
        float acc = lin2_b[o];
#pragma unroll
        for (int u = 0; u < 10; ++u)
            acc = fmaf(zs[b][u], lin2_W[o * 10 + u], acc);
        out[b * 2 + o] = acc;
    }
}

// ---------------------------------------------------------------------------
extern "C" void kernel_launch(void* const* d_in, const int* in_sizes, int n_in,
                              void* d_out, int out_size, void* d_ws, size_t ws_size,
                              hipStream_t stream) {
    const float* input  = (const float*)d_in[0];
    const float* pca_W  = (const float*)d_in[1];
    const float* pca_b  = (const float*)d_in[2];
    const float* W_ih0  = (const float*)d_in[3];
    const float* W_hh0  = (const float*)d_in[4];
    const float* b0     = (const float*)d_in[5];
    const float* W_ih1  = (const float*)d_in[6];
    const float* W_hh1  = (const float*)d_in[7];
    const float* b1     = (const float*)d_in[8];
    const float* h0     = (const float*)d_in[9];
    const float* c0     = (const float*)d_in[10];
    const float* lin1_W = (const float*)d_in[11];
    const float* lin1_b = (const float*)d_in[12];
    const float* lin2_W = (const float*)d_in[13];
    const float* lin2_b = (const float*)d_in[14];
    float* out = (float*)d_out;

    float* ws = (float*)d_ws;
    size_t off = 0;
    float* xg   = ws + off; off += (size_t)B_ * T_ * NG_;  // 52.4M floats
    float* xbuf = ws + off; off += (size_t)B_ * T_ * H_;   // 13.1M floats
    float* hs0  = xbuf;                                    // alias: xbuf dead before hs0 born
    float* hT0  = ws + off; off += H_ * BP;
    float* hT1  = ws + off; off += H_ * BP;
    float* wt0  = ws + off; off += (size_t)NBLK * 512 * 8; // 1.05M floats
    float* wt1  = ws + off; off += (size_t)NBLK * 512 * 8;
    int*   flg  = (int*)(ws + off); off += 2 * (NBLK + 8) * FLS;
    int* mflag0 = flg;
    int* lflag0 = flg + NBLK * FLS;
    int* mflag1 = flg + (NBLK + 8) * FLS;
    int* lflag1 = mflag1 + NBLK * FLS;

    const int M = B_ * T_;  // 25600

    // zero all flags (ws is poisoned 0xAA; 0xAAAAAAAA<0 would never terminate polls)
    hipMemsetAsync(flg, 0, 2 * (NBLK + 8) * FLS * sizeof(int), stream);

    // pre-transpose W_hh slices
    w_transpose<<<NBLK, 256, 0, stream>>>(W_hh0, wt0);
    w_transpose<<<NBLK, 256, 0, stream>>>(W_hh1, wt1);

    // 1. pca: xbuf = input @ pca_W^T + pca_b   (M x 512, K=1024)
    {
        dim3 g(H_ / 128, M / 128);
        gemm_bias<<<g, 256, 0, stream>>>(input, pca_W, pca_b, xbuf, M, H_, I_);
    }
    // 2. xg0 = xbuf @ W_ih0^T + b0             (M x 2048, K=512)
    {
        dim3 g(NG_ / 128, M / 128);
        gemm_bias<<<g, 256, 0, stream>>>(xbuf, W_ih0, b0, xg, M, NG_, H_);
    }
    // 3. layer-0 scan (persistent; writes hs0)
    init_state<<<(H_ * BP) / 256, 256, 0, stream>>>(h0, hT0, hT1);
    lstm_scan<<<NBLK, 256, 0, stream>>>(xg, hT0, hT1, c0, wt0, hs0, mflag0, lflag0);
    // 4. xg1 = hs0 @ W_ih1^T + b1
    {
        dim3 g(NG_ / 128, M / 128);
        gemm_bias<<<g, 256, 0, stream>>>(hs0, W_ih1, b1, xg, M, NG_, H_);
    }
    // 5. layer-1 scan (final h lands in hT0 since T even)
    init_state<<<(H_ * BP) / 256, 256, 0, stream>>>(h0 + B_ * H_, hT0, hT1);
    lstm_scan<<<NBLK, 256, 0, stream>>>(xg, hT0, hT1, c0 + B_ * H_, wt1, nullptr,
                                        mflag1, lflag1);
    // 6. head
    head<<<1, 512, 0, stream>>>(hT0, lin1_W, lin1_b, lin2_W, lin2_b, out);
}

// Round 5
// 12575.230 us; speedup vs baseline: 4.3305x; 2.6144x over previous
//
#include <hip/hip_runtime.h>
#include <math.h>

#define B_  50
#define T_  512
#define I_  1024
#define H_  512
#define NG_ 2048
#define NBLK 256  // 8 groups x 32 blocks, 1 block/CU
#define FLS  32   // flag stride in ints (128 B per flag line)

__device__ __forceinline__ float sigmf(float x) {
    return 1.0f / (1.0f + __expf(-x));
}
// overflow-safe tanh via e^{-2|x|} in (0,1]
__device__ __forceinline__ float tanh_fast(float x) {
    float ax = fabsf(x);
    float e  = __expf(-2.0f * ax);
    float t  = (1.0f - e) / (1.0f + e);
    return copysignf(t, x);
}

// ---------------------------------------------------------------------------
// C[m][n] = bias[n] + sum_k A[m][k] * W[n][k]
// 128x128 tile, K-step 16, 256 threads, 8x8 accum per thread.
// ---------------------------------------------------------------------------
__global__ __launch_bounds__(256) void gemm_bias(
    const float* __restrict__ A, const float* __restrict__ W,
    const float* __restrict__ bias, float* __restrict__ C,
    int M, int N, int K) {
    __shared__ float As[16][132];
    __shared__ float Ws[16][132];
    const int tid = threadIdx.x;
    const int m0 = blockIdx.y * 128, n0 = blockIdx.x * 128;
    const int lr = tid >> 2;
    const int lk = (tid & 3) << 2;
    const int tx = tid & 15, ty = tid >> 4;

    float acc[8][8];
#pragma unroll
    for (int i = 0; i < 8; ++i)
#pragma unroll
        for (int j = 0; j < 8; ++j) acc[i][j] = 0.0f;

    for (int k0 = 0; k0 < K; k0 += 16) {
        float4 a0 = *(const float4*)(A + (size_t)(m0 + lr) * K + k0 + lk);
        float4 a1 = *(const float4*)(A + (size_t)(m0 + lr + 64) * K + k0 + lk);
        float4 w0 = *(const float4*)(W + (size_t)(n0 + lr) * K + k0 + lk);
        float4 w1 = *(const float4*)(W + (size_t)(n0 + lr + 64) * K + k0 + lk);
        __syncthreads();
        As[lk + 0][lr] = a0.x; As[lk + 1][lr] = a0.y; As[lk + 2][lr] = a0.z; As[lk + 3][lr] = a0.w;
        As[lk + 0][lr + 64] = a1.x; As[lk + 1][lr + 64] = a1.y; As[lk + 2][lr + 64] = a1.z; As[lk + 3][lr + 64] = a1.w;
        Ws[lk + 0][lr] = w0.x; Ws[lk + 1][lr] = w0.y; Ws[lk + 2][lr] = w0.z; Ws[lk + 3][lr] = w0.w;
        Ws[lk + 0][lr + 64] = w1.x; Ws[lk + 1][lr + 64] = w1.y; Ws[lk + 2][lr + 64] = w1.z; Ws[lk + 3][lr + 64] = w1.w;
        __syncthreads();
#pragma unroll
        for (int k = 0; k < 16; ++k) {
            const float4 av0 = *(const float4*)&As[k][tx * 4];
            const float4 av1 = *(const float4*)&As[k][64 + tx * 4];
            const float4 bv0 = *(const float4*)&Ws[k][ty * 4];
            const float4 bv1 = *(const float4*)&Ws[k][64 + ty * 4];
            float a[8] = {av0.x, av0.y, av0.z, av0.w, av1.x, av1.y, av1.z, av1.w};
            float b[8] = {bv0.x, bv0.y, bv0.z, bv0.w, bv1.x, bv1.y, bv1.z, bv1.w};
#pragma unroll
            for (int i = 0; i < 8; ++i)
#pragma unroll
                for (int j = 0; j < 8; ++j) acc[i][j] = fmaf(a[i], b[j], acc[i][j]);
        }
    }

    const float4 bv0 = *(const float4*)&bias[n0 + ty * 4];
    const float4 bv1 = *(const float4*)&bias[n0 + 64 + ty * 4];
    const float bb[8] = {bv0.x, bv0.y, bv0.z, bv0.w, bv1.x, bv1.y, bv1.z, bv1.w};
#pragma unroll
    for (int i = 0; i < 8; ++i) {
        int m = m0 + ((i < 4) ? (tx * 4 + i) : (64 + tx * 4 + (i - 4)));
        float4 v0, v1;
        v0.x = acc[i][0] + bb[0]; v0.y = acc[i][1] + bb[1];
        v0.z = acc[i][2] + bb[2]; v0.w = acc[i][3] + bb[3];
        v1.x = acc[i][4] + bb[4]; v1.y = acc[i][5] + bb[5];
        v1.z = acc[i][6] + bb[6]; v1.w = acc[i][7] + bb[7];
        *(float4*)&C[(size_t)m * N + n0 + ty * 4] = v0;
        *(float4*)&C[(size_t)m * N + n0 + 64 + ty * 4] = v1;
    }
}

// ---------------------------------------------------------------------------
// hA[b][j] = h0[b][j] (b<50 else 0), layout [64][H]
// ---------------------------------------------------------------------------
__global__ void init_state(const float* __restrict__ h0, float* __restrict__ hA) {
    int idx = blockIdx.x * blockDim.x + threadIdx.x;
    if (idx >= 64 * H_) return;
    int b = idx >> 9;
    hA[idx] = (b < B_) ? h0[idx - ((b - 0) * 0)] * 0.0f + h0[b * H_ + (idx & (H_ - 1))] : 0.0f;
}

// ---------------------------------------------------------------------------
// Persistent LSTM scan, fence-free. 8 groups x 32 blocks. Group g owns
// batches [bat0, bat0+cnt) (7,7,6,6,6,6,6,6). Block (g,m) owns 64 gate rows:
// gates i/f/g/o for h-components j0=m*16 .. j0+15. W slice lives in 128
// VGPRs per thread (thread (r=tid&63, s=tid>>6): row r, k-chunk s*128).
// Cross-block h exchange + flags via RELAXED agent-scope atomics only — no
// acquire/release fences -> no buffer_wbl2/buffer_inv L2 thrash. Ordering:
// __syncthreads drains stores (vmcnt 0) before the epoch-flag store; readers
// poll flags before touching h (atomics are agent-coherent at L3).
// ---------------------------------------------------------------------------
__global__ __launch_bounds__(256, 1) void lstm_scan(
    const float* __restrict__ xg,     // [B][T][NG], bias included
    float* __restrict__ hA,           // [64][H] state entering even steps
    float* __restrict__ hB,           // [64][H] state entering odd steps
    const float* __restrict__ c0,     // [B][H] initial cell state (layer slice)
    const float* __restrict__ W_hh,   // [NG][H]
    float* __restrict__ hs,           // [B][T][H] or nullptr
    int* __restrict__ flags) {        // NBLK*FLS ints, zeroed
    __shared__ float h_lds[7 * H_];   // 14 KB (group batch slice of h)
    __shared__ float red[4 * 64 * 7]; // 7 KB  (split-k partials)
    __shared__ float xt[64 * 7];      // 1.75 KB (this step's xg tile)
    const int tid = threadIdx.x;
    const int bid = blockIdx.x;
    const int g   = bid >> 5;         // group 0..7
    const int m   = bid & 31;
    const int j0  = m * 16;
    const int bat0 = (g < 2) ? 7 * g : 14 + 6 * (g - 2);
    const int cnt  = (g < 2) ? 7 : 6;

    const int r = tid & 63;           // gate-row slot: gate=r>>4, jl=r&15
    const int s = tid >> 6;           // k-chunk 0..3
    const int grow = (r >> 4) * H_ + j0 + (r & 15);

    // W slice -> registers (one-time; 32 float4 = 128 VGPRs)
    float4 w4[32];
    {
        const float* wp = W_hh + (size_t)grow * H_ + s * 128;
#pragma unroll
        for (int i = 0; i < 32; ++i) w4[i] = *(const float4*)(wp + 4 * i);
    }

    // phase-2 (gate) identity: thread tid<128 -> (jl=tid>>3, bq=tid&7)
    const int jl2 = tid >> 3;
    const int bq  = tid & 7;
    const bool wr = (tid < 128) && (bq < cnt);
    float creg = 0.0f;
    if (wr) creg = c0[(size_t)(bat0 + bq) * H_ + j0 + jl2];

    int* myflag = flags + (size_t)bid * FLS;
    const int fbase = g * 32;

    for (int t = 0; t < T_; ++t) {
        const float* hin  = (t & 1) ? hB : hA;
        float*       hout = (t & 1) ? hA : hB;

        // ---- stage group h slice (contiguous batches) + xg tile ----
        {
            const unsigned long long* src =
                (const unsigned long long*)(hin + (size_t)bat0 * H_);
            unsigned long long* dst = (unsigned long long*)h_lds;
            for (int i = tid; i < cnt * 256; i += 256)
                dst[i] = __hip_atomic_load(src + i, __ATOMIC_RELAXED,
                                           __HIP_MEMORY_SCOPE_AGENT);
            for (int i = tid; i < cnt * 64; i += 256) {
                int b = i >> 6, rr = i & 63;
                int row = (rr >> 4) * H_ + j0 + (rr & 15);
                xt[rr * 7 + b] = xg[((size_t)(bat0 + b) * T_ + t) * NG_ + row];
            }
        }
        __syncthreads();

        // ---- phase 1: W(regs) x h(LDS broadcast) over 128-k chunk ----
        float ax[7], ay[7];
#pragma unroll
        for (int b = 0; b < 7; ++b) { ax[b] = 0.0f; ay[b] = 0.0f; }
        const int kb0 = s * 128;
#pragma unroll
        for (int i = 0; i < 32; ++i) {
            const float4 w = w4[i];
#pragma unroll
            for (int b = 0; b < 7; ++b) {
                const float4 h = *(const float4*)&h_lds[b * H_ + kb0 + 4 * i];
                ax[b] = fmaf(w.x, h.x, ax[b]);
                ay[b] = fmaf(w.y, h.y, ay[b]);
                ax[b] = fmaf(w.z, h.z, ax[b]);
                ay[b] = fmaf(w.w, h.w, ay[b]);
            }
        }
#pragma unroll
        for (int b = 0; b < 7; ++b)
            red[(s * 64 + r) * 7 + b] = ax[b] + ay[b];
        __syncthreads();

        // ---- phase 2: reduce + gates; c in registers ----
        if (wr) {
            float gv[4];
#pragma unroll
            for (int gt = 0; gt < 4; ++gt) {
                int rr = gt * 16 + jl2;
                gv[gt] = red[(0 * 64 + rr) * 7 + bq] + red[(1 * 64 + rr) * 7 + bq]
                       + red[(2 * 64 + rr) * 7 + bq] + red[(3 * 64 + rr) * 7 + bq]
                       + xt[rr * 7 + bq];
            }
            float cn = sigmf(gv[1]) * creg + sigmf(gv[0]) * tanh_fast(gv[2]);
            float hn = sigmf(gv[3]) * tanh_fast(cn);
            creg = cn;
            __hip_atomic_store(hout + (size_t)(bat0 + bq) * H_ + j0 + jl2, hn,
                               __ATOMIC_RELAXED, __HIP_MEMORY_SCOPE_AGENT);
            if (hs) hs[((size_t)(bat0 + bq) * T_ + t) * H_ + j0 + jl2] = hn;
        }
        __syncthreads();  // drains all waves' stores (vmcnt 0 before s_barrier)

        // ---- intra-group epoch barrier, fence-free ----
        if (tid == 0) {
            asm volatile("s_waitcnt vmcnt(0)" ::: "memory");
            __hip_atomic_store(myflag, t + 1, __ATOMIC_RELAXED,
                               __HIP_MEMORY_SCOPE_AGENT);
        }
        if (tid < 64) {
            const int tgt = t + 1;
            const int* f = flags + (size_t)(fbase + (tid & 31)) * FLS;
            for (;;) {
                int v = (tid < 32)
                    ? __hip_atomic_load(f, __ATOMIC_RELAXED, __HIP_MEMORY_SCOPE_AGENT)
                    : tgt;
                if (__all(v >= tgt)) break;
                __builtin_amdgcn_s_sleep(1);
            }
        }
        __syncthreads();
    }
}

// ---------------------------------------------------------------------------
// head: hT layout [b][H] (b < 50 valid)
// ---------------------------------------------------------------------------
__global__ __launch_bounds__(512) void head(
    const float* __restrict__ hT, const float* __restrict__ lin1_W,
    const float* __restrict__ lin1_b, const float* __restrict__ lin2_W,
    const float* __restrict__ lin2_b, float* __restrict__ out) {
    __shared__ float zs[B_][10];
    int tid = threadIdx.x;
    if (tid < B_ * 10) {
        int b = tid / 10, u = tid % 10;
        float acc = lin1_b[u];
        for (int j = 0; j < H_; ++j)
            acc = fmaf(hT[(size_t)b * H_ + j], lin1_W[u * H_ + j], acc);
        zs[b][u] = tanh_fast(acc);
    }
    __syncthreads();
    if (tid < B_ * 2) {
        int b = tid >> 1, o = tid & 1;
        float acc = lin2_b[o];
#pragma unroll
        for (int u = 0; u < 10; ++u)
            acc = fmaf(zs[b][u], lin2_W[o * 10 + u], acc);
        out[b * 2 + o] = acc;
    }
}

// ---------------------------------------------------------------------------
extern "C" void kernel_launch(void* const* d_in, const int* in_sizes, int n_in,
                              void* d_out, int out_size, void* d_ws, size_t ws_size,
                              hipStream_t stream) {
    const float* input  = (const float*)d_in[0];
    const float* pca_W  = (const float*)d_in[1];
    const float* pca_b  = (const float*)d_in[2];
    const float* W_ih0  = (const float*)d_in[3];
    const float* W_hh0  = (const float*)d_in[4];
    const float* b0     = (const float*)d_in[5];
    const float* W_ih1  = (const float*)d_in[6];
    const float* W_hh1  = (const float*)d_in[7];
    const float* b1     = (const float*)d_in[8];
    const float* h0     = (const float*)d_in[9];
    const float* c0     = (const float*)d_in[10];
    const float* lin1_W = (const float*)d_in[11];
    const float* lin1_b = (const float*)d_in[12];
    const float* lin2_W = (const float*)d_in[13];
    const float* lin2_b = (const float*)d_in[14];
    float* out = (float*)d_out;

    float* ws = (float*)d_ws;
    size_t off = 0;
    float* xg   = ws + off; off += (size_t)B_ * T_ * NG_;  // 52.4M floats
    float* xbuf = ws + off; off += (size_t)B_ * T_ * H_;   // 13.1M floats
    float* hs0  = xbuf;                                    // alias: xbuf dead before hs0 born
    float* hTA  = ws + off; off += 64 * H_;
    float* hTB  = ws + off; off += 64 * H_;
    int*   flg0 = (int*)(ws + off); off += NBLK * FLS;
    int*   flg1 = (int*)(ws + off); off += NBLK * FLS;

    const int M = B_ * T_;  // 25600

    // flags must start at 0 (ws re-poisoned 0xAA before every timed launch)
    hipMemsetAsync(flg0, 0, 2 * NBLK * FLS * sizeof(int), stream);

    // 1. pca: xbuf = input @ pca_W^T + pca_b   (M x 512, K=1024)
    {
        dim3 g(H_ / 128, M / 128);
        gemm_bias<<<g, 256, 0, stream>>>(input, pca_W, pca_b, xbuf, M, H_, I_);
    }
    // 2. xg0 = xbuf @ W_ih0^T + b0             (M x 2048, K=512)
    {
        dim3 g(NG_ / 128, M / 128);
        gemm_bias<<<g, 256, 0, stream>>>(xbuf, W_ih0, b0, xg, M, NG_, H_);
    }
    // 3. layer-0 scan (persistent; writes hs0)
    init_state<<<(64 * H_) / 256, 256, 0, stream>>>(h0, hTA);
    lstm_scan<<<NBLK, 256, 0, stream>>>(xg, hTA, hTB, c0, W_hh0, hs0, flg0);
    // 4. xg1 = hs0 @ W_ih1^T + b1
    {
        dim3 g(NG_ / 128, M / 128);
        gemm_bias<<<g, 256, 0, stream>>>(hs0, W_ih1, b1, xg, M, NG_, H_);
    }
    // 5. layer-1 scan (final h lands in hTA since T even: t=511 odd writes A)
    init_state<<<(64 * H_) / 256, 256, 0, stream>>>(h0 + B_ * H_, hTA);
    lstm_scan<<<NBLK, 256, 0, stream>>>(xg, hTA, hTB, c0 + B_ * H_, W_hh1,
                                        nullptr, flg1);
    // 6. head
    head<<<1, 512, 0, stream>>>(hTA, lin1_W, lin1_b, lin2_W, lin2_b, out);
}

// Round 6
// 6529.749 us; speedup vs baseline: 8.3398x; 1.9258x over previous
//
#include <hip/hip_runtime.h>
#include <math.h>

#define B_  50
#define T_  512
#define I_  1024
#define H_  512
#define NG_ 2048
#define NBLK 256  // 8 groups x 32 blocks, 1 block/CU
#define FLS  32   // flag stride in ints (128 B per flag line)

typedef __attribute__((ext_vector_type(8))) short short8;   // 8 bf16 (4 VGPRs)
typedef __attribute__((ext_vector_type(4))) float f32x4;    // MFMA accumulator
typedef unsigned short ushort_t;
typedef unsigned long long ull_t;

__device__ __forceinline__ float sigmf(float x) {
    return 1.0f / (1.0f + __expf(-x));
}
// overflow-safe tanh via e^{-2|x|} in (0,1]
__device__ __forceinline__ float tanh_fast(float x) {
    float ax = fabsf(x);
    float e  = __expf(-2.0f * ax);
    float t  = (1.0f - e) / (1.0f + e);
    return copysignf(t, x);
}
__device__ __forceinline__ ushort_t bf16_rne(float x) {
    unsigned u = __float_as_uint(x);
    unsigned r = u + 0x7fffu + ((u >> 16) & 1u);
    return (ushort_t)(r >> 16);
}
__device__ __forceinline__ float bf16_tof(ushort_t h) {
    return __uint_as_float(((unsigned)h) << 16);
}

// ---------------------------------------------------------------------------
// C[m][n] = bias[n] + sum_k A[m][k] * W[n][k]
// 128x128 tile, K-step 16, 256 threads, 8x8 accum per thread.
// ---------------------------------------------------------------------------
__global__ __launch_bounds__(256) void gemm_bias(
    const float* __restrict__ A, const float* __restrict__ W,
    const float* __restrict__ bias, float* __restrict__ C,
    int M, int N, int K) {
    __shared__ float As[16][132];
    __shared__ float Ws[16][132];
    const int tid = threadIdx.x;
    const int m0 = blockIdx.y * 128, n0 = blockIdx.x * 128;
    const int lr = tid >> 2;
    const int lk = (tid & 3) << 2;
    const int tx = tid & 15, ty = tid >> 4;

    float acc[8][8];
#pragma unroll
    for (int i = 0; i < 8; ++i)
#pragma unroll
        for (int j = 0; j < 8; ++j) acc[i][j] = 0.0f;

    for (int k0 = 0; k0 < K; k0 += 16) {
        float4 a0 = *(const float4*)(A + (size_t)(m0 + lr) * K + k0 + lk);
        float4 a1 = *(const float4*)(A + (size_t)(m0 + lr + 64) * K + k0 + lk);
        float4 w0 = *(const float4*)(W + (size_t)(n0 + lr) * K + k0 + lk);
        float4 w1 = *(const float4*)(W + (size_t)(n0 + lr + 64) * K + k0 + lk);
        __syncthreads();
        As[lk + 0][lr] = a0.x; As[lk + 1][lr] = a0.y; As[lk + 2][lr] = a0.z; As[lk + 3][lr] = a0.w;
        As[lk + 0][lr + 64] = a1.x; As[lk + 1][lr + 64] = a1.y; As[lk + 2][lr + 64] = a1.z; As[lk + 3][lr + 64] = a1.w;
        Ws[lk + 0][lr] = w0.x; Ws[lk + 1][lr] = w0.y; Ws[lk + 2][lr] = w0.z; Ws[lk + 3][lr] = w0.w;
        Ws[lk + 0][lr + 64] = w1.x; Ws[lk + 1][lr + 64] = w1.y; Ws[lk + 2][lr + 64] = w1.z; Ws[lk + 3][lr + 64] = w1.w;
        __syncthreads();
#pragma unroll
        for (int k = 0; k < 16; ++k) {
            const float4 av0 = *(const float4*)&As[k][tx * 4];
            const float4 av1 = *(const float4*)&As[k][64 + tx * 4];
            const float4 bv0 = *(const float4*)&Ws[k][ty * 4];
            const float4 bv1 = *(const float4*)&Ws[k][64 + ty * 4];
            float a[8] = {av0.x, av0.y, av0.z, av0.w, av1.x, av1.y, av1.z, av1.w};
            float b[8] = {bv0.x, bv0.y, bv0.z, bv0.w, bv1.x, bv1.y, bv1.z, bv1.w};
#pragma unroll
            for (int i = 0; i < 8; ++i)
#pragma unroll
                for (int j = 0; j < 8; ++j) acc[i][j] = fmaf(a[i], b[j], acc[i][j]);
        }
    }

    const float4 bv0 = *(const float4*)&bias[n0 + ty * 4];
    const float4 bv1 = *(const float4*)&bias[n0 + 64 + ty * 4];
    const float bb[8] = {bv0.x, bv0.y, bv0.z, bv0.w, bv1.x, bv1.y, bv1.z, bv1.w};
#pragma unroll
    for (int i = 0; i < 8; ++i) {
        int m = m0 + ((i < 4) ? (tx * 4 + i) : (64 + tx * 4 + (i - 4)));
        float4 v0, v1;
        v0.x = acc[i][0] + bb[0]; v0.y = acc[i][1] + bb[1];
        v0.z = acc[i][2] + bb[2]; v0.w = acc[i][3] + bb[3];
        v1.x = acc[i][4] + bb[4]; v1.y = acc[i][5] + bb[5];
        v1.z = acc[i][6] + bb[6]; v1.w = acc[i][7] + bb[7];
        *(float4*)&C[(size_t)m * N + n0 + ty * 4] = v0;
        *(float4*)&C[(size_t)m * N + n0 + 64 + ty * 4] = v1;
    }
}

// ---------------------------------------------------------------------------
// Build compressed A-fragment buffer from h0 (one block per group).
// Layout per group (8192 ushorts): [hl(2)][ks(16)][cl(32)][jj(8)],
// cl = m' + 8*oct, element = h[bat0+m'][ks*32 + oct*8 + jj] as bf16 hi/lo.
// ---------------------------------------------------------------------------
__global__ __launch_bounds__(256) void init_hfrag(
    const float* __restrict__ h0, ushort_t* __restrict__ hf) {
    const int g = blockIdx.x, tid = threadIdx.x;
    const int bat0 = (g < 2) ? 7 * g : 14 + 6 * (g - 2);
    const int cnt  = (g < 2) ? 7 : 6;
    ushort_t* og = hf + (size_t)g * 8192;
    for (int i = tid; i < 8192; i += 256) {
        int jj = i & 7, cl = (i >> 3) & 31, ks = (i >> 8) & 15, hl = i >> 12;
        int m = cl & 7, oct = cl >> 3;
        int j = ks * 32 + oct * 8 + jj;
        float x = 0.0f;
        if (m < cnt) x = h0[(size_t)(bat0 + m) * H_ + j];
        ushort_t hi = bf16_rne(x);
        og[i] = hl ? bf16_rne(x - bf16_tof(hi)) : hi;
    }
}

// ---------------------------------------------------------------------------
// Persistent MFMA LSTM scan. 8 groups x 32 blocks; block (g,m) owns gates
// i/f/g/o for h-components j0=m*16..j0+15 (4 16-row MFMA B-tiles).
// W in VGPRs as split-bf16 B-fragments (wave w = k-slice [128w,128w+128)).
// h exchanged as pre-converted split-bf16 A-fragments via relaxed agent
// atomics (L3-coherent, no fences -> no L2 writeback/invalidate storms).
// Per step: stage 16KB frags->LDS, 48 MFMAs/wave, LDS split-K reduce,
// 56-thread gate phase, intra-group flag barrier.
// ---------------------------------------------------------------------------
__global__ __launch_bounds__(256, 1) void lstm_scan(
    const float* __restrict__ xg,     // [B][T][NG], bias included
    ushort_t* __restrict__ hfA,       // frag state entering even t
    ushort_t* __restrict__ hfB,       // frag state entering odd t
    const float* __restrict__ c0,     // [B][H] initial cell (layer slice)
    const float* __restrict__ W_hh,   // [NG][H]
    float* __restrict__ hplain,       // [B][H] plain h (final state for head)
    float* __restrict__ hs,           // [B][T][H] or nullptr
    int* __restrict__ flags) {        // NBLK*FLS ints, zeroed
    __shared__ ushort_t lds_hf[16384];        // 32 KB [hl][ks][lane64][8]
    __shared__ float d_lds[4 * 4 * 8 * 16];   // 8 KB [wave][gate][m(8)][jl(16)]
    const int tid = threadIdx.x, bid = blockIdx.x;
    const int g = bid >> 5, mB = bid & 31;
    const int j0 = mB * 16;
    const int bat0 = (g < 2) ? 7 * g : 14 + 6 * (g - 2);
    const int cnt  = (g < 2) ? 7 : 6;
    const int w = tid >> 6, L = tid & 63;

    // zero pad lanes (m>=8) once; stage loop never touches them
    {
        ull_t* lu = (ull_t*)lds_hf;
        for (int i = tid; i < 4096; i += 256)
            if ((((i >> 1) & 63) & 15) >= 8) lu[i] = 0ULL;
    }

    // ---- one-time W B-frag preload (128 VGPRs: 4 gates x 4 ks x hi/lo) ----
    short8 Bhi[4][4], Blo[4][4];
    {
        const int n = L & 15, oct = L >> 4;
#pragma unroll
        for (int q = 0; q < 4; ++q) {
            const float* wr = W_hh + (size_t)(q * H_ + j0 + n) * H_;
#pragma unroll
            for (int kk = 0; kk < 4; ++kk) {
                int kbase = (w * 4 + kk) * 32 + oct * 8;
                float4 f0 = *(const float4*)(wr + kbase);
                float4 f1 = *(const float4*)(wr + kbase + 4);
                float xs[8] = {f0.x, f0.y, f0.z, f0.w, f1.x, f1.y, f1.z, f1.w};
                union { ushort_t s[8]; short8 v; } uh, ul;
#pragma unroll
                for (int e = 0; e < 8; ++e) {
                    ushort_t hi = bf16_rne(xs[e]);
                    uh.s[e] = hi;
                    ul.s[e] = bf16_rne(xs[e] - bf16_tof(hi));
                }
                Bhi[q][kk] = uh.v;
                Blo[q][kk] = ul.v;
            }
        }
    }

    // ---- gate-phase identity: tid<56 -> (m=tid>>3, j-pair jlp=(tid&7)*2) ----
    const int gm = tid >> 3, jlp = (tid & 7) * 2;
    const bool gok = (tid < 56) && (gm < cnt);
    const int gb = (bat0 + gm < B_) ? bat0 + gm : B_ - 1;  // clamped for prefetch
    float ca = 0.0f, cb = 0.0f;
    if (gok) {
        ca = c0[(size_t)gb * H_ + j0 + jlp];
        cb = c0[(size_t)gb * H_ + j0 + jlp + 1];
    }
    float2 xr[4];
    if (tid < 56) {
#pragma unroll
        for (int q = 0; q < 4; ++q)
            xr[q] = *(const float2*)(xg + ((size_t)gb * T_) * NG_ + q * H_ + j0 + jlp);
    }

    int* myflag = flags + (size_t)bid * FLS;
    const int fbase = g * 32;
    const short8* ap = (const short8*)lds_hf;
    const f32x4 vzero = {0.f, 0.f, 0.f, 0.f};

    for (int t = 0; t < T_; ++t) {
        const ushort_t* hf_in = (t & 1) ? hfB : hfA;
        ushort_t*       hf_out = (t & 1) ? hfA : hfB;

        // ---- stage compressed group frags (16 KB) -> LDS expanded ----
        {
            const ull_t* src = (const ull_t*)(hf_in + (size_t)g * 8192);
            ull_t* lu = (ull_t*)lds_hf;
#pragma unroll
            for (int i = 0; i < 8; ++i) {
                int u = tid + i * 256;
                ull_t v = __hip_atomic_load(src + u, __ATOMIC_RELAXED,
                                            __HIP_MEMORY_SCOPE_AGENT);
                int jjh = u & 1, cl = (u >> 1) & 31, ks = (u >> 6) & 15, hl = (u >> 10) & 1;
                int el = (cl & 7) + 16 * (cl >> 3);
                lu[((hl * 16 + ks) * 64 + el) * 2 + jjh] = v;
            }
        }
        __syncthreads();

        // ---- MFMA: wave w covers ks'=4w..4w+3, 4 gate tiles, split-bf16 ----
        f32x4 acc[4];
#pragma unroll
        for (int q = 0; q < 4; ++q) acc[q] = vzero;
#pragma unroll
        for (int kk = 0; kk < 4; ++kk) {
            int ksp = w * 4 + kk;
            short8 Ahi = ap[ksp * 64 + L];
            short8 Alo = ap[1024 + ksp * 64 + L];
#pragma unroll
            for (int q = 0; q < 4; ++q) {
                acc[q] = __builtin_amdgcn_mfma_f32_16x16x32_bf16(Ahi, Bhi[q][kk], acc[q], 0, 0, 0);
                acc[q] = __builtin_amdgcn_mfma_f32_16x16x32_bf16(Alo, Bhi[q][kk], acc[q], 0, 0, 0);
                acc[q] = __builtin_amdgcn_mfma_f32_16x16x32_bf16(Ahi, Blo[q][kk], acc[q], 0, 0, 0);
            }
        }
        // D[m=(L>>4)*4+r][n=L&15]; keep batch rows m<8
#pragma unroll
        for (int q = 0; q < 4; ++q) {
#pragma unroll
            for (int r = 0; r < 4; ++r) {
                int m = (L >> 4) * 4 + r;
                if (m < 8) d_lds[((w * 4 + q) * 8 + m) * 16 + (L & 15)] = acc[q][r];
            }
        }
        __syncthreads();

        // ---- gate phase (56 threads, 2 components each) ----
        if (gok) {
            float ga[4], gbv[4];
#pragma unroll
            for (int q = 0; q < 4; ++q) {
                float sx = 0.f, sy = 0.f;
#pragma unroll
                for (int ww = 0; ww < 4; ++ww) {
                    const float2 p = *(const float2*)&d_lds[((ww * 4 + q) * 8 + gm) * 16 + jlp];
                    sx += p.x; sy += p.y;
                }
                ga[q]  = sx + xr[q].x;
                gbv[q] = sy + xr[q].y;
            }
            float cna = sigmf(ga[1]) * ca + sigmf(ga[0]) * tanh_fast(ga[2]);
            float hna = sigmf(ga[3]) * tanh_fast(cna);
            float cnb = sigmf(gbv[1]) * cb + sigmf(gbv[0]) * tanh_fast(gbv[2]);
            float hnb = sigmf(gbv[3]) * tanh_fast(cnb);
            ca = cna; cb = cnb;
            // publish split-bf16 frags (relaxed agent atomics, L3-coherent)
            ushort_t hia = bf16_rne(hna), hib = bf16_rne(hnb);
            ushort_t loa = bf16_rne(hna - bf16_tof(hia));
            ushort_t lob = bf16_rne(hnb - bf16_tof(hib));
            int jA = j0 + jlp;
            int cl = gm + 8 * ((jA >> 3) & 3);
            int ks = jA >> 5, jj = jA & 7;
            ushort_t* og = hf_out + (size_t)g * 8192;
            unsigned hv = (unsigned)hia | ((unsigned)hib << 16);
            unsigned lv = (unsigned)loa | ((unsigned)lob << 16);
            __hip_atomic_store((unsigned*)(og + (ks * 256 + cl * 8 + jj)), hv,
                               __ATOMIC_RELAXED, __HIP_MEMORY_SCOPE_AGENT);
            __hip_atomic_store((unsigned*)(og + (4096 + ks * 256 + cl * 8 + jj)), lv,
                               __ATOMIC_RELAXED, __HIP_MEMORY_SCOPE_AGENT);
            // plain history / final state (consumed after kernel boundary)
            *(float2*)(hplain + (size_t)gb * H_ + jA) = make_float2(hna, hnb);
            if (hs) *(float2*)(hs + ((size_t)gb * T_ + t) * H_ + jA) = make_float2(hna, hnb);
        }
        __syncthreads();   // all stores drained (vmcnt0 before s_barrier)

        if (tid == 0) {
            asm volatile("s_waitcnt vmcnt(0)" ::: "memory");
            __hip_atomic_store(myflag, t + 1, __ATOMIC_RELAXED,
                               __HIP_MEMORY_SCOPE_AGENT);
        }
        // prefetch next xg tile during the poll window
        if (tid < 56 && t + 1 < T_) {
#pragma unroll
            for (int q = 0; q < 4; ++q)
                xr[q] = *(const float2*)(xg + ((size_t)gb * T_ + (t + 1)) * NG_ + q * H_ + j0 + jlp);
        }
        if (tid < 64) {
            const int tgt = t + 1;
            const int* f = flags + (size_t)(fbase + (tid & 31)) * FLS;
            for (;;) {
                int v = (tid < 32)
                    ? __hip_atomic_load(f, __ATOMIC_RELAXED, __HIP_MEMORY_SCOPE_AGENT)
                    : tgt;
                if (__all(v >= tgt)) break;
                __builtin_amdgcn_s_sleep(1);
            }
        }
        __syncthreads();
    }
}

// ---------------------------------------------------------------------------
// head: hT layout [b][H]
// ---------------------------------------------------------------------------
__global__ __launch_bounds__(512) void head(
    const float* __restrict__ hT, const float* __restrict__ lin1_W,
    const float* __restrict__ lin1_b, const float* __restrict__ lin2_W,
    const float* __restrict__ lin2_b, float* __restrict__ out) {
    __shared__ float zs[B_][10];
    int tid = threadIdx.x;
    if (tid < B_ * 10) {
        int b = tid / 10, u = tid % 10;
        float acc = lin1_b[u];
        for (int j = 0; j < H_; ++j)
            acc = fmaf(hT[(size_t)b * H_ + j], lin1_W[u * H_ + j], acc);
        zs[b][u] = tanh_fast(acc);
    }
    __syncthreads();
    if (tid < B_ * 2) {
        int b = tid >> 1, o = tid & 1;
        float acc = lin2_b[o];
#pragma unroll
        for (int u = 0; u < 10; ++u)
            acc = fmaf(zs[b][u], lin2_W[o * 10 + u], acc);
        out[b * 2 + o] = acc;
    }
}

// ---------------------------------------------------------------------------
extern "C" void kernel_launch(void* const* d_in, const int* in_sizes, int n_in,
                              void* d_out, int out_size, void* d_ws, size_t ws_size,
                              hipStream_t stream) {
    const float* input  = (const float*)d_in[0];
    const float* pca_W  = (const float*)d_in[1];
    const float* pca_b  = (const float*)d_in[2];
    const float* W_ih0  = (const float*)d_in[3];
    const float* W_hh0  = (const float*)d_in[4];
    const float* b0     = (const float*)d_in[5];
    const float* W_ih1  = (const float*)d_in[6];
    const float* W_hh1  = (const float*)d_in[7];
    const float* b1     = (const float*)d_in[8];
    const float* h0     = (const float*)d_in[9];
    const float* c0     = (const float*)d_in[10];
    const float* lin1_W = (const float*)d_in[11];
    const float* lin1_b = (const float*)d_in[12];
    const float* lin2_W = (const float*)d_in[13];
    const float* lin2_b = (const float*)d_in[14];
    float* out = (float*)d_out;

    float* ws = (float*)d_ws;
    size_t off = 0;
    float* xg     = ws + off; off += (size_t)B_ * T_ * NG_;  // 52.4M floats
    float* xbuf   = ws + off; off += (size_t)B_ * T_ * H_;   // 13.1M floats
    float* hs0    = xbuf;                                    // alias: xbuf dead before hs0 born
    float* hplain = ws + off; off += B_ * H_;
    ushort_t* hfA = (ushort_t*)(ws + off); off += 32768;     // 8 groups x 16 KB
    ushort_t* hfB = (ushort_t*)(ws + off); off += 32768;
    int* flg0 = (int*)(ws + off); off += NBLK * FLS;
    int* flg1 = (int*)(ws + off); off += NBLK * FLS;

    const int M = B_ * T_;  // 25600

    // flags must start at 0 (ws re-poisoned 0xAA before every timed launch)
    hipMemsetAsync(flg0, 0, 2 * NBLK * FLS * sizeof(int), stream);

    // 1. pca: xbuf = input @ pca_W^T + pca_b   (M x 512, K=1024)
    {
        dim3 g(H_ / 128, M / 128);
        gemm_bias<<<g, 256, 0, stream>>>(input, pca_W, pca_b, xbuf, M, H_, I_);
    }
    // 2. xg0 = xbuf @ W_ih0^T + b0             (M x 2048, K=512)
    {
        dim3 g(NG_ / 128, M / 128);
        gemm_bias<<<g, 256, 0, stream>>>(xbuf, W_ih0, b0, xg, M, NG_, H_);
    }
    // 3. layer-0 scan
    init_hfrag<<<8, 256, 0, stream>>>(h0, hfA);
    lstm_scan<<<NBLK, 256, 0, stream>>>(xg, hfA, hfB, c0, W_hh0, hplain, hs0, flg0);
    // 4. xg1 = hs0 @ W_ih1^T + b1
    {
        dim3 g(NG_ / 128, M / 128);
        gemm_bias<<<g, 256, 0, stream>>>(hs0, W_ih1, b1, xg, M, NG_, H_);
    }
    // 5. layer-1 scan (hplain ends as final h)
    init_hfrag<<<8, 256, 0, stream>>>(h0 + B_ * H_, hfA);
    lstm_scan<<<NBLK, 256, 0, stream>>>(xg, hfA, hfB, c0 + B_ * H_, W_hh1, hplain,
                                        nullptr, flg1);
    // 6. head
    head<<<1, 512, 0, stream>>>(hplain, lin1_W, lin1_b, lin2_W, lin2_b, out);
}

// Round 7
// 4694.698 us; speedup vs baseline: 11.5996x; 1.3909x over previous
//
#include <hip/hip_runtime.h>
#include <math.h>

#define B_  50
#define T_  512
#define I_  1024
#define H_  512
#define NG_ 2048
#define NBLK 256  // 8 groups x 32 blocks, 1 block/CU
#define FLS  32   // flag stride in ints (128 B per flag line)

typedef __attribute__((ext_vector_type(8))) short short8;   // 8 bf16 (4 VGPRs)
typedef __attribute__((ext_vector_type(4))) float f32x4;    // MFMA accumulator
typedef unsigned short ushort_t;
typedef unsigned long long ull_t;

__device__ __forceinline__ float sigmf(float x) {
    return 1.0f / (1.0f + __expf(-x));
}
// overflow-safe tanh via e^{-2|x|} in (0,1]
__device__ __forceinline__ float tanh_fast(float x) {
    float ax = fabsf(x);
    float e  = __expf(-2.0f * ax);
    float t  = (1.0f - e) / (1.0f + e);
    return copysignf(t, x);
}
__device__ __forceinline__ ushort_t bf16_rne(float x) {
    unsigned u = __float_as_uint(x);
    unsigned r = u + 0x7fffu + ((u >> 16) & 1u);
    return (ushort_t)(r >> 16);
}
__device__ __forceinline__ float bf16_tof(ushort_t h) {
    return __uint_as_float(((unsigned)h) << 16);
}

// ---------------------------------------------------------------------------
// C[m][n] = bias[n] + sum_k A[m][k] * W[n][k].  128x128 tile, fp32 SIMT.
// tmode=1: store row m to ((m % T) * B + m / T)  (xg -> [T][B][NG] layout).
// ---------------------------------------------------------------------------
__global__ __launch_bounds__(256) void gemm_bias(
    const float* __restrict__ A, const float* __restrict__ W,
    const float* __restrict__ bias, float* __restrict__ C,
    int M, int N, int K, int tmode) {
    __shared__ float As[16][132];
    __shared__ float Ws[16][132];
    const int tid = threadIdx.x;
    const int m0 = blockIdx.y * 128, n0 = blockIdx.x * 128;
    const int lr = tid >> 2;
    const int lk = (tid & 3) << 2;
    const int tx = tid & 15, ty = tid >> 4;

    float acc[8][8];
#pragma unroll
    for (int i = 0; i < 8; ++i)
#pragma unroll
        for (int j = 0; j < 8; ++j) acc[i][j] = 0.0f;

    for (int k0 = 0; k0 < K; k0 += 16) {
        float4 a0 = *(const float4*)(A + (size_t)(m0 + lr) * K + k0 + lk);
        float4 a1 = *(const float4*)(A + (size_t)(m0 + lr + 64) * K + k0 + lk);
        float4 w0 = *(const float4*)(W + (size_t)(n0 + lr) * K + k0 + lk);
        float4 w1 = *(const float4*)(W + (size_t)(n0 + lr + 64) * K + k0 + lk);
        __syncthreads();
        As[lk + 0][lr] = a0.x; As[lk + 1][lr] = a0.y; As[lk + 2][lr] = a0.z; As[lk + 3][lr] = a0.w;
        As[lk + 0][lr + 64] = a1.x; As[lk + 1][lr + 64] = a1.y; As[lk + 2][lr + 64] = a1.z; As[lk + 3][lr + 64] = a1.w;
        Ws[lk + 0][lr] = w0.x; Ws[lk + 1][lr] = w0.y; Ws[lk + 2][lr] = w0.z; Ws[lk + 3][lr] = w0.w;
        Ws[lk + 0][lr + 64] = w1.x; Ws[lk + 1][lr + 64] = w1.y; Ws[lk + 2][lr + 64] = w1.z; Ws[lk + 3][lr + 64] = w1.w;
        __syncthreads();
#pragma unroll
        for (int k = 0; k < 16; ++k) {
            const float4 av0 = *(const float4*)&As[k][tx * 4];
            const float4 av1 = *(const float4*)&As[k][64 + tx * 4];
            const float4 bv0 = *(const float4*)&Ws[k][ty * 4];
            const float4 bv1 = *(const float4*)&Ws[k][64 + ty * 4];
            float a[8] = {av0.x, av0.y, av0.z, av0.w, av1.x, av1.y, av1.z, av1.w};
            float b[8] = {bv0.x, bv0.y, bv0.z, bv0.w, bv1.x, bv1.y, bv1.z, bv1.w};
#pragma unroll
            for (int i = 0; i < 8; ++i)
#pragma unroll
                for (int j = 0; j < 8; ++j) acc[i][j] = fmaf(a[i], b[j], acc[i][j]);
        }
    }

    const float4 bv0 = *(const float4*)&bias[n0 + ty * 4];
    const float4 bv1 = *(const float4*)&bias[n0 + 64 + ty * 4];
    const float bb[8] = {bv0.x, bv0.y, bv0.z, bv0.w, bv1.x, bv1.y, bv1.z, bv1.w};
#pragma unroll
    for (int i = 0; i < 8; ++i) {
        int m = m0 + ((i < 4) ? (tx * 4 + i) : (64 + tx * 4 + (i - 4)));
        size_t crow = tmode ? ((size_t)(m & (T_ - 1)) * B_ + (m >> 9)) : (size_t)m;
        float4 v0, v1;
        v0.x = acc[i][0] + bb[0]; v0.y = acc[i][1] + bb[1];
        v0.z = acc[i][2] + bb[2]; v0.w = acc[i][3] + bb[3];
        v1.x = acc[i][4] + bb[4]; v1.y = acc[i][5] + bb[5];
        v1.z = acc[i][6] + bb[6]; v1.w = acc[i][7] + bb[7];
        *(float4*)&C[crow * N + n0 + ty * 4] = v0;
        *(float4*)&C[crow * N + n0 + 64 + ty * 4] = v1;
    }
}

// ---------------------------------------------------------------------------
// Build compressed A-fragment buffer from an h state (one block per group).
// Layout per group (8192 ushorts): [hl(2)][ks(16)][cl(32)][jj(8)],
// cl = m' + 8*oct, element = h[bat0+m'][ks*32 + oct*8 + jj] as bf16 hi/lo.
// ---------------------------------------------------------------------------
__global__ __launch_bounds__(256) void init_hfrag(
    const float* __restrict__ h0, ushort_t* __restrict__ hf) {
    const int g = blockIdx.x, tid = threadIdx.x;
    const int bat0 = (g < 2) ? 7 * g : 14 + 6 * (g - 2);
    const int cnt  = (g < 2) ? 7 : 6;
    ushort_t* og = hf + (size_t)g * 8192;
    for (int i = tid; i < 8192; i += 256) {
        int jj = i & 7, cl = (i >> 3) & 31, ks = (i >> 8) & 15, hl = i >> 12;
        int m = cl & 7, oct = cl >> 3;
        int j = ks * 32 + oct * 8 + jj;
        float x = 0.0f;
        if (m < cnt) x = h0[(size_t)(bat0 + m) * H_ + j];
        ushort_t hi = bf16_rne(x);
        og[i] = hl ? bf16_rne(x - bf16_tof(hi)) : hi;
    }
}

// ---------------------------------------------------------------------------
// Fused 2-layer persistent LSTM scan, software-pipelined: at super-step s,
// layer0 computes t=s (s<T), layer1 computes t=s-1 (s>=1). 513 super-steps.
// 8 groups x 32 blocks; block (g,mB) owns components j0=16*mB..j0+15 of BOTH
// layers' h, all 4 gates. W_hh0/W_hh1 split-bf16 in regs (256 VGPRs);
// W_ih1 hi in regs (64), lo manually spilled to LDS (64 KB).
// h exchanged as split-bf16 A-frags via relaxed agent atomics (L3-coherent,
// no acquire/release -> no L2 wb/inv storms). Per-wave flags: wave0 signals
// h0 published, wave1 signals h1; consumers poll 64 flags (2/block).
// ---------------------------------------------------------------------------
__global__ __launch_bounds__(256, 1) void lstm_fused(
    const float* __restrict__ xg,     // [T][B][NG] layer0 gates, bias included
    ushort_t* __restrict__ hf0A, ushort_t* __restrict__ hf0B,
    ushort_t* __restrict__ hf1A, ushort_t* __restrict__ hf1B,
    const float* __restrict__ c0,     // [2][B][H]
    const float* __restrict__ W_hh0,  // [NG][H]
    const float* __restrict__ W_hh1,  // [NG][H]
    const float* __restrict__ W_ih1,  // [NG][H]
    const float* __restrict__ b1,     // [NG]
    float* __restrict__ hplain,       // [B][H] final layer-1 h
    int* __restrict__ flags) {        // NBLK*FLS ints, zeroed
    __shared__ ushort_t hfL0[16384];          // 32 KB expanded h0 A-frags
    __shared__ ushort_t hfL1[16384];          // 32 KB expanded h1 A-frags
    __shared__ float d0[4 * 4 * 8 * 16];      // 8 KB layer0 partials
    __shared__ float d1[4 * 4 * 8 * 16];      // 8 KB layer1 partials
    __shared__ short8 wlo[4 * 4 * 4 * 64];    // 64 KB W_ih1 lo B-frags
    const int tid = threadIdx.x, bid = blockIdx.x;
    const int g = bid >> 5, mB = bid & 31;
    const int j0 = mB * 16;
    const int bat0 = (g < 2) ? 7 * g : 14 + 6 * (g - 2);
    const int cnt  = (g < 2) ? 7 : 6;
    const int w = tid >> 6, L = tid & 63;

    // zero pad lanes (m>=8) of both frag buffers
    {
        ull_t* u0 = (ull_t*)hfL0;
        ull_t* u1 = (ull_t*)hfL1;
        for (int i = tid; i < 4096; i += 256)
            if ((((i >> 1) & 63) & 15) >= 8) { u0[i] = 0ULL; u1[i] = 0ULL; }
    }

    // ---- one-time W preload ----
    short8 Bhh0h[4][4], Bhh0l[4][4], Bhh1h[4][4], Bhh1l[4][4], Bih1h[4][4];
    {
        const int n = L & 15, oct = L >> 4;
#pragma unroll
        for (int q = 0; q < 4; ++q) {
            const size_t row = (size_t)(q * H_ + j0 + n) * H_;
#pragma unroll
            for (int kk = 0; kk < 4; ++kk) {
                int kbase = (w * 4 + kk) * 32 + oct * 8;
                // W_hh0
                {
                    float4 f0 = *(const float4*)(W_hh0 + row + kbase);
                    float4 f1 = *(const float4*)(W_hh0 + row + kbase + 4);
                    float xs[8] = {f0.x, f0.y, f0.z, f0.w, f1.x, f1.y, f1.z, f1.w};
                    union { ushort_t s[8]; short8 v; } uh, ul;
#pragma unroll
                    for (int e = 0; e < 8; ++e) {
                        ushort_t hi = bf16_rne(xs[e]);
                        uh.s[e] = hi; ul.s[e] = bf16_rne(xs[e] - bf16_tof(hi));
                    }
                    Bhh0h[q][kk] = uh.v; Bhh0l[q][kk] = ul.v;
                }
                // W_hh1
                {
                    float4 f0 = *(const float4*)(W_hh1 + row + kbase);
                    float4 f1 = *(const float4*)(W_hh1 + row + kbase + 4);
                    float xs[8] = {f0.x, f0.y, f0.z, f0.w, f1.x, f1.y, f1.z, f1.w};
                    union { ushort_t s[8]; short8 v; } uh, ul;
#pragma unroll
                    for (int e = 0; e < 8; ++e) {
                        ushort_t hi = bf16_rne(xs[e]);
                        uh.s[e] = hi; ul.s[e] = bf16_rne(xs[e] - bf16_tof(hi));
                    }
                    Bhh1h[q][kk] = uh.v; Bhh1l[q][kk] = ul.v;
                }
                // W_ih1: hi -> regs, lo -> LDS
                {
                    float4 f0 = *(const float4*)(W_ih1 + row + kbase);
                    float4 f1 = *(const float4*)(W_ih1 + row + kbase + 4);
                    float xs[8] = {f0.x, f0.y, f0.z, f0.w, f1.x, f1.y, f1.z, f1.w};
                    union { ushort_t s[8]; short8 v; } uh, ul;
#pragma unroll
                    for (int e = 0; e < 8; ++e) {
                        ushort_t hi = bf16_rne(xs[e]);
                        uh.s[e] = hi; ul.s[e] = bf16_rne(xs[e] - bf16_tof(hi));
                    }
                    Bih1h[q][kk] = uh.v;
                    wlo[((w * 4 + q) * 4 + kk) * 64 + L] = ul.v;
                }
            }
        }
    }

    // ---- gate-phase identities ----
    // wave0 (layer0): tid<56 -> (gm0=tid>>3, jlp0=(tid&7)*2)
    const int gm0 = tid >> 3, jlp0 = (tid & 7) * 2;
    const bool gok0 = (tid < 56) && (gm0 < cnt);
    const int gb0 = (bat0 + gm0 < B_) ? bat0 + gm0 : B_ - 1;
    float c0a = 0.f, c0b = 0.f;
    if (gok0) {
        c0a = c0[(size_t)gb0 * H_ + j0 + jlp0];
        c0b = c0[(size_t)gb0 * H_ + j0 + jlp0 + 1];
    }
    float2 xr[4];
    if (tid < 56) {
#pragma unroll
        for (int q = 0; q < 4; ++q)
            xr[q] = *(const float2*)(xg + (size_t)gb0 * NG_ + q * H_ + j0 + jlp0);
    }
    // wave1 (layer1): tid in [64,120) -> (gm1, jlp1)
    const int u1 = tid - 64;
    const int gm1 = u1 >> 3, jlp1 = (u1 & 7) * 2;
    const bool gok1 = (tid >= 64) && (tid < 120) && (gm1 < cnt);
    const int gb1 = (gok1 && bat0 + gm1 < B_) ? bat0 + gm1 : B_ - 1;
    float c1a = 0.f, c1b = 0.f;
    float2 b1r[4];
    if (gok1) {
        c1a = c0[(size_t)(B_ + gb1) * H_ + j0 + jlp1];
        c1b = c0[(size_t)(B_ + gb1) * H_ + j0 + jlp1 + 1];
#pragma unroll
        for (int q = 0; q < 4; ++q)
            b1r[q] = *(const float2*)(b1 + q * H_ + j0 + jlp1);
    }

    __syncthreads();   // wlo + pad-zero visible

    const short8* ap0 = (const short8*)hfL0;
    const short8* ap1 = (const short8*)hfL1;
    const f32x4 vzero = {0.f, 0.f, 0.f, 0.f};

    for (int s = 0; s <= T_; ++s) {
        const ushort_t* r0 = (s & 1) ? hf0A : hf0B;   // h0(s-1)
        ushort_t*       w0 = (s & 1) ? hf0B : hf0A;
        const ushort_t* r1 = (s & 1) ? hf1B : hf1A;   // h1(s-2)
        ushort_t*       w1 = (s & 1) ? hf1A : hf1B;

        // ---- stage both frag sets -> LDS expanded ----
        {
            const ull_t* s0 = (const ull_t*)(r0 + (size_t)g * 8192);
            const ull_t* s1 = (const ull_t*)(r1 + (size_t)g * 8192);
            ull_t* l0 = (ull_t*)hfL0;
            ull_t* l1 = (ull_t*)hfL1;
#pragma unroll
            for (int i = 0; i < 8; ++i) {
                int u = tid + i * 256;
                ull_t v0 = __hip_atomic_load(s0 + u, __ATOMIC_RELAXED, __HIP_MEMORY_SCOPE_AGENT);
                ull_t v1 = __hip_atomic_load(s1 + u, __ATOMIC_RELAXED, __HIP_MEMORY_SCOPE_AGENT);
                int jjh = u & 1, cl = (u >> 1) & 31, ks = (u >> 6) & 15, hl = (u >> 10) & 1;
                int el = (cl & 7) + 16 * (cl >> 3);
                int di = ((hl * 16 + ks) * 64 + el) * 2 + jjh;
                l0[di] = v0;
                l1[di] = v1;
            }
        }
        __syncthreads();

        // ---- layer-0 MFMA (t0 = s) ----
        if (s < T_) {
            f32x4 acc[4];
#pragma unroll
            for (int q = 0; q < 4; ++q) acc[q] = vzero;
#pragma unroll
            for (int kk = 0; kk < 4; ++kk) {
                int ksp = w * 4 + kk;
                short8 Ahi = ap0[ksp * 64 + L];
                short8 Alo = ap0[1024 + ksp * 64 + L];
#pragma unroll
                for (int q = 0; q < 4; ++q) {
                    acc[q] = __builtin_amdgcn_mfma_f32_16x16x32_bf16(Ahi, Bhh0h[q][kk], acc[q], 0, 0, 0);
                    acc[q] = __builtin_amdgcn_mfma_f32_16x16x32_bf16(Alo, Bhh0h[q][kk], acc[q], 0, 0, 0);
                    acc[q] = __builtin_amdgcn_mfma_f32_16x16x32_bf16(Ahi, Bhh0l[q][kk], acc[q], 0, 0, 0);
                }
            }
#pragma unroll
            for (int q = 0; q < 4; ++q)
#pragma unroll
                for (int r = 0; r < 4; ++r) {
                    int m = (L >> 4) * 4 + r;
                    if (m < 8) d0[((w * 4 + q) * 8 + m) * 16 + (L & 15)] = acc[q][r];
                }
        }
        // ---- layer-1 MFMA (t1 = s-1): W_ih1@h0(s-1) + W_hh1@h1(s-2) ----
        if (s >= 1) {
            f32x4 acc[4];
#pragma unroll
            for (int q = 0; q < 4; ++q) acc[q] = vzero;
#pragma unroll
            for (int kk = 0; kk < 4; ++kk) {
                int ksp = w * 4 + kk;
                short8 A0h = ap0[ksp * 64 + L];
                short8 A0l = ap0[1024 + ksp * 64 + L];
                short8 A1h = ap1[ksp * 64 + L];
                short8 A1l = ap1[1024 + ksp * 64 + L];
#pragma unroll
                for (int q = 0; q < 4; ++q) {
                    short8 Wl = wlo[((w * 4 + q) * 4 + kk) * 64 + L];
                    acc[q] = __builtin_amdgcn_mfma_f32_16x16x32_bf16(A0h, Bih1h[q][kk], acc[q], 0, 0, 0);
                    acc[q] = __builtin_amdgcn_mfma_f32_16x16x32_bf16(A0l, Bih1h[q][kk], acc[q], 0, 0, 0);
                    acc[q] = __builtin_amdgcn_mfma_f32_16x16x32_bf16(A0h, Wl, acc[q], 0, 0, 0);
                    acc[q] = __builtin_amdgcn_mfma_f32_16x16x32_bf16(A1h, Bhh1h[q][kk], acc[q], 0, 0, 0);
                    acc[q] = __builtin_amdgcn_mfma_f32_16x16x32_bf16(A1l, Bhh1h[q][kk], acc[q], 0, 0, 0);
                    acc[q] = __builtin_amdgcn_mfma_f32_16x16x32_bf16(A1h, Bhh1l[q][kk], acc[q], 0, 0, 0);
                }
            }
#pragma unroll
            for (int q = 0; q < 4; ++q)
#pragma unroll
                for (int r = 0; r < 4; ++r) {
                    int m = (L >> 4) * 4 + r;
                    if (m < 8) d1[((w * 4 + q) * 8 + m) * 16 + (L & 15)] = acc[q][r];
                }
        }
        __syncthreads();

        // ---- layer-0 gate phase (wave 0) + flagA ----
        if (s < T_) {
            if (gok0) {
                float ga[4], gb[4];
#pragma unroll
                for (int q = 0; q < 4; ++q) {
                    float sx = 0.f, sy = 0.f;
#pragma unroll
                    for (int ww = 0; ww < 4; ++ww) {
                        const float2 p = *(const float2*)&d0[((ww * 4 + q) * 8 + gm0) * 16 + jlp0];
                        sx += p.x; sy += p.y;
                    }
                    ga[q] = sx + xr[q].x;
                    gb[q] = sy + xr[q].y;
                }
                float cna = sigmf(ga[1]) * c0a + sigmf(ga[0]) * tanh_fast(ga[2]);
                float hna = sigmf(ga[3]) * tanh_fast(cna);
                float cnb = sigmf(gb[1]) * c0b + sigmf(gb[0]) * tanh_fast(gb[2]);
                float hnb = sigmf(gb[3]) * tanh_fast(cnb);
                c0a = cna; c0b = cnb;
                ushort_t hia = bf16_rne(hna), hib = bf16_rne(hnb);
                ushort_t loa = bf16_rne(hna - bf16_tof(hia));
                ushort_t lob = bf16_rne(hnb - bf16_tof(hib));
                int jA = j0 + jlp0;
                int cl = gm0 + 8 * ((jA >> 3) & 3);
                int ks = jA >> 5, jj = jA & 7;
                ushort_t* og = w0 + (size_t)g * 8192;
                unsigned hv = (unsigned)hia | ((unsigned)hib << 16);
                unsigned lv = (unsigned)loa | ((unsigned)lob << 16);
                __hip_atomic_store((unsigned*)(og + (ks * 256 + cl * 8 + jj)), hv,
                                   __ATOMIC_RELAXED, __HIP_MEMORY_SCOPE_AGENT);
                __hip_atomic_store((unsigned*)(og + (4096 + ks * 256 + cl * 8 + jj)), lv,
                                   __ATOMIC_RELAXED, __HIP_MEMORY_SCOPE_AGENT);
            }
        }
        if (tid == 0) {
            asm volatile("s_waitcnt vmcnt(0)" ::: "memory");
            __hip_atomic_store(flags + (size_t)bid * FLS + 0, s + 1,
                               __ATOMIC_RELAXED, __HIP_MEMORY_SCOPE_AGENT);
        }
        // prefetch next xg tile (after flagA so it doesn't delay the signal)
        if (tid < 56 && s + 1 < T_) {
#pragma unroll
            for (int q = 0; q < 4; ++q)
                xr[q] = *(const float2*)(xg + ((size_t)(s + 1) * B_ + gb0) * NG_ + q * H_ + j0 + jlp0);
        }

        // ---- layer-1 gate phase (wave 1) + flagB ----
        if (s >= 1 && gok1) {
            float ga[4], gb[4];
#pragma unroll
            for (int q = 0; q < 4; ++q) {
                float sx = 0.f, sy = 0.f;
#pragma unroll
                for (int ww = 0; ww < 4; ++ww) {
                    const float2 p = *(const float2*)&d1[((ww * 4 + q) * 8 + gm1) * 16 + jlp1];
                    sx += p.x; sy += p.y;
                }
                ga[q] = sx + b1r[q].x;
                gb[q] = sy + b1r[q].y;
            }
            float cna = sigmf(ga[1]) * c1a + sigmf(ga[0]) * tanh_fast(ga[2]);
            float hna = sigmf(ga[3]) * tanh_fast(cna);
            float cnb = sigmf(gb[1]) * c1b + sigmf(gb[0]) * tanh_fast(gb[2]);
            float hnb = sigmf(gb[3]) * tanh_fast(cnb);
            c1a = cna; c1b = cnb;
            ushort_t hia = bf16_rne(hna), hib = bf16_rne(hnb);
            ushort_t loa = bf16_rne(hna - bf16_tof(hia));
            ushort_t lob = bf16_rne(hnb - bf16_tof(hib));
            int jA = j0 + jlp1;
            int cl = gm1 + 8 * ((jA >> 3) & 3);
            int ks = jA >> 5, jj = jA & 7;
            ushort_t* og = w1 + (size_t)g * 8192;
            unsigned hv = (unsigned)hia | ((unsigned)hib << 16);
            unsigned lv = (unsigned)loa | ((unsigned)lob << 16);
            __hip_atomic_store((unsigned*)(og + (ks * 256 + cl * 8 + jj)), hv,
                               __ATOMIC_RELAXED, __HIP_MEMORY_SCOPE_AGENT);
            __hip_atomic_store((unsigned*)(og + (4096 + ks * 256 + cl * 8 + jj)), lv,
                               __ATOMIC_RELAXED, __HIP_MEMORY_SCOPE_AGENT);
            if (s == T_) *(float2*)(hplain + (size_t)gb1 * H_ + jA) = make_float2(hna, hnb);
        }
        if (tid == 64) {
            asm volatile("s_waitcnt vmcnt(0)" ::: "memory");
            __hip_atomic_store(flags + (size_t)bid * FLS + 1, s + 1,
                               __ATOMIC_RELAXED, __HIP_MEMORY_SCOPE_AGENT);
        }

        // ---- poll: wave 0 checks both flags of all 32 group blocks ----
        if (tid < 64) {
            const int tgt = s + 1;
            const int* f = flags + (size_t)(g * 32 + (tid & 31)) * FLS + (tid >> 5);
            for (;;) {
                int v = __hip_atomic_load(f, __ATOMIC_RELAXED, __HIP_MEMORY_SCOPE_AGENT);
                if (__all(v >= tgt)) break;
                __builtin_amdgcn_s_sleep(1);
            }
        }
        __syncthreads();
    }
}

// ---------------------------------------------------------------------------
// head: hT layout [b][H]
// ---------------------------------------------------------------------------
__global__ __launch_bounds__(512) void head(
    const float* __restrict__ hT, const float* __restrict__ lin1_W,
    const float* __restrict__ lin1_b, const float* __restrict__ lin2_W,
    const float* __restrict__ lin2_b, float* __restrict__ out) {
    __shared__ float zs[B_][10];
    int tid = threadIdx.x;
    if (tid < B_ * 10) {
        int b = tid / 10, u = tid % 10;
        float acc = lin1_b[u];
        for (int j = 0; j < H_; ++j)
            acc = fmaf(hT[(size_t)b * H_ + j], lin1_W[u * H_ + j], acc);
        zs[b][u] = tanh_fast(acc);
    }
    __syncthreads();
    if (tid < B_ * 2) {
        int b = tid >> 1, o = tid & 1;
        float acc = lin2_b[o];
#pragma unroll
        for (int u = 0; u < 10; ++u)
            acc = fmaf(zs[b][u], lin2_W[o * 10 + u], acc);
        out[b * 2 + o] = acc;
    }
}

// ---------------------------------------------------------------------------
extern "C" void kernel_launch(void* const* d_in, const int* in_sizes, int n_in,
                              void* d_out, int out_size, void* d_ws, size_t ws_size,
                              hipStream_t stream) {
    const float* input  = (const float*)d_in[0];
    const float* pca_W  = (const float*)d_in[1];
    const float* pca_b  = (const float*)d_in[2];
    const float* W_ih0  = (const float*)d_in[3];
    const float* W_hh0  = (const float*)d_in[4];
    const float* b0     = (const float*)d_in[5];
    const float* W_ih1  = (const float*)d_in[6];
    const float* W_hh1  = (const float*)d_in[7];
    const float* b1     = (const float*)d_in[8];
    const float* h0     = (const float*)d_in[9];
    const float* c0     = (const float*)d_in[10];
    const float* lin1_W = (const float*)d_in[11];
    const float* lin1_b = (const float*)d_in[12];
    const float* lin2_W = (const float*)d_in[13];
    const float* lin2_b = (const float*)d_in[14];
    float* out = (float*)d_out;

    float* ws = (float*)d_ws;
    size_t off = 0;
    float* xg     = ws + off; off += (size_t)B_ * T_ * NG_;  // [T][B][NG]
    float* xbuf   = ws + off; off += (size_t)B_ * T_ * H_;
    float* hplain = ws + off; off += B_ * H_;
    ushort_t* hf0A = (ushort_t*)(ws + off); off += 32768;    // 8 x 8192 ushorts
    ushort_t* hf0B = (ushort_t*)(ws + off); off += 32768;
    ushort_t* hf1A = (ushort_t*)(ws + off); off += 32768;
    ushort_t* hf1B = (ushort_t*)(ws + off); off += 32768;
    int* flg = (int*)(ws + off); off += NBLK * FLS;

    const int M = B_ * T_;  // 25600

    // flags must start at 0 (ws re-poisoned 0xAA before every timed launch)
    hipMemsetAsync(flg, 0, NBLK * FLS * sizeof(int), stream);

    // initial states -> frag buffers (read at s=0 / s=1 respectively)
    init_hfrag<<<8, 256, 0, stream>>>(h0, hf0B);
    init_hfrag<<<8, 256, 0, stream>>>(h0 + B_ * H_, hf1B);

    // 1. pca: xbuf = input @ pca_W^T + pca_b   (row-major [B*T][H])
    {
        dim3 g(H_ / 128, M / 128);
        gemm_bias<<<g, 256, 0, stream>>>(input, pca_W, pca_b, xbuf, M, H_, I_, 0);
    }
    // 2. xg0 = xbuf @ W_ih0^T + b0, stored [T][B][NG]
    {
        dim3 g(NG_ / 128, M / 128);
        gemm_bias<<<g, 256, 0, stream>>>(xbuf, W_ih0, b0, xg, M, NG_, H_, 1);
    }
    // 3. fused 2-layer pipelined scan
    lstm_fused<<<NBLK, 256, 0, stream>>>(xg, hf0A, hf0B, hf1A, hf1B, c0,
                                         W_hh0, W_hh1, W_ih1, b1, hplain, flg);
    // 4. head
    head<<<1, 512, 0, stream>>>(hplain, lin1_W, lin1_b, lin2_W, lin2_b, out);
}

// Round 8
// 4143.727 us; speedup vs baseline: 13.1419x; 1.1330x over previous
//
#include <hip/hip_runtime.h>
#include <math.h>

#define B_  50
#define T_  512
#define I_  1024
#define H_  512
#define NG_ 2048
#define NBLK 256  // 8 groups x 32 blocks, 1 block/CU
#define FLS  32   // flag stride in ints (128 B per flag line)

typedef __attribute__((ext_vector_type(8))) short short8;   // 8 bf16 (4 VGPRs)
typedef __attribute__((ext_vector_type(4))) float f32x4;    // MFMA accumulator
typedef unsigned short ushort_t;
typedef unsigned long long ull_t;

__device__ __forceinline__ float sigmf(float x) {
    return 1.0f / (1.0f + __expf(-x));
}
// overflow-safe tanh via e^{-2|x|} in (0,1]
__device__ __forceinline__ float tanh_fast(float x) {
    float ax = fabsf(x);
    float e  = __expf(-2.0f * ax);
    float t  = (1.0f - e) / (1.0f + e);
    return copysignf(t, x);
}
__device__ __forceinline__ ushort_t bf16_rne(float x) {
    unsigned u = __float_as_uint(x);
    unsigned r = u + 0x7fffu + ((u >> 16) & 1u);
    return (ushort_t)(r >> 16);
}
__device__ __forceinline__ float bf16_tof(ushort_t h) {
    return __uint_as_float(((unsigned)h) << 16);
}

// ---------------------------------------------------------------------------
// MFMA split-bf16 GEMM: C[m][n] = bias[n] + sum_k A[m][k] * W[n][k].
// 128x128 tile, BK=32, 4 waves x (4x4 16x16x32 tiles), 3 products per tile
// (AhiBhi + AloBhi + AhiBlo) for ~fp32 accuracy. LDS frag arrays padded to
// stride 40 ushorts (80 B) -> conflict-free ds_read_b128.
// tmode=1: store row m to ((m % T)*B + m/T)  (xg -> [T][B][NG] layout).
// ---------------------------------------------------------------------------
__global__ __launch_bounds__(256) void gemm_bias_mfma(
    const float* __restrict__ A, const float* __restrict__ W,
    const float* __restrict__ bias, float* __restrict__ C,
    int M, int N, int K, int tmode) {
    __shared__ ushort_t Ah[128 * 40];
    __shared__ ushort_t Al[128 * 40];
    __shared__ ushort_t Wh[128 * 40];
    __shared__ ushort_t Wl[128 * 40];
    const int tid = threadIdx.x;
    const int m0 = blockIdx.y * 128, n0 = blockIdx.x * 128;
    const int w = tid >> 6, L = tid & 63;
    const int wm = (w & 1) * 64, wn = (w >> 1) * 64;
    const int rr = tid >> 1, kh = (tid & 1) << 4;

    f32x4 acc[4][4];
#pragma unroll
    for (int i = 0; i < 4; ++i)
#pragma unroll
        for (int j = 0; j < 4; ++j) acc[i][j] = (f32x4){0.f, 0.f, 0.f, 0.f};

    for (int k0 = 0; k0 < K; k0 += 32) {
        float4 av[4], wv[4];
        const float* ap = A + (size_t)(m0 + rr) * K + k0 + kh;
        const float* wp = W + (size_t)(n0 + rr) * K + k0 + kh;
#pragma unroll
        for (int e = 0; e < 4; ++e) {
            av[e] = *(const float4*)(ap + 4 * e);
            wv[e] = *(const float4*)(wp + 4 * e);
        }
        __syncthreads();   // previous iter's frag reads complete
        union { ushort_t s[16]; ull_t u[4]; } ha, la, hw, lw;
#pragma unroll
        for (int e = 0; e < 4; ++e) {
            float as[4] = {av[e].x, av[e].y, av[e].z, av[e].w};
            float ws[4] = {wv[e].x, wv[e].y, wv[e].z, wv[e].w};
#pragma unroll
            for (int f = 0; f < 4; ++f) {
                ushort_t hi = bf16_rne(as[f]);
                ha.s[e * 4 + f] = hi;
                la.s[e * 4 + f] = bf16_rne(as[f] - bf16_tof(hi));
                hi = bf16_rne(ws[f]);
                hw.s[e * 4 + f] = hi;
                lw.s[e * 4 + f] = bf16_rne(ws[f] - bf16_tof(hi));
            }
        }
        {
            ull_t* d0 = (ull_t*)&Ah[rr * 40 + kh];
            ull_t* d1 = (ull_t*)&Al[rr * 40 + kh];
            ull_t* d2 = (ull_t*)&Wh[rr * 40 + kh];
            ull_t* d3 = (ull_t*)&Wl[rr * 40 + kh];
#pragma unroll
            for (int e = 0; e < 4; ++e) {
                d0[e] = ha.u[e]; d1[e] = la.u[e];
                d2[e] = hw.u[e]; d3[e] = lw.u[e];
            }
        }
        __syncthreads();
        const int ko = (L >> 4) * 8;
        short8 ahf[4], alf[4], whf[4], wlf[4];
#pragma unroll
        for (int i = 0; i < 4; ++i) {
            ahf[i] = *(const short8*)&Ah[(wm + i * 16 + (L & 15)) * 40 + ko];
            alf[i] = *(const short8*)&Al[(wm + i * 16 + (L & 15)) * 40 + ko];
            whf[i] = *(const short8*)&Wh[(wn + i * 16 + (L & 15)) * 40 + ko];
            wlf[i] = *(const short8*)&Wl[(wn + i * 16 + (L & 15)) * 40 + ko];
        }
#pragma unroll
        for (int i = 0; i < 4; ++i)
#pragma unroll
            for (int j = 0; j < 4; ++j) {
                acc[i][j] = __builtin_amdgcn_mfma_f32_16x16x32_bf16(ahf[i], whf[j], acc[i][j], 0, 0, 0);
                acc[i][j] = __builtin_amdgcn_mfma_f32_16x16x32_bf16(alf[i], whf[j], acc[i][j], 0, 0, 0);
                acc[i][j] = __builtin_amdgcn_mfma_f32_16x16x32_bf16(ahf[i], wlf[j], acc[i][j], 0, 0, 0);
            }
    }

    // epilogue: D[row=(L>>4)*4+r][col=L&15] per tile
#pragma unroll
    for (int j = 0; j < 4; ++j) {
        int col = n0 + wn + j * 16 + (L & 15);
        float bv = bias[col];
#pragma unroll
        for (int i = 0; i < 4; ++i) {
#pragma unroll
            for (int r = 0; r < 4; ++r) {
                int row = m0 + wm + i * 16 + (L >> 4) * 4 + r;
                size_t crow = tmode ? ((size_t)(row & (T_ - 1)) * B_ + (row >> 9))
                                    : (size_t)row;
                C[crow * N + col] = acc[i][j][r] + bv;
            }
        }
    }
}

// ---------------------------------------------------------------------------
// Build compressed A-fragment buffer from an h state (one block per group).
// Layout per group (8192 ushorts): [hl(2)][ks(16)][cl(32)][jj(8)],
// cl = m' + 8*oct, element = h[bat0+m'][ks*32 + oct*8 + jj] as bf16 hi/lo.
// ---------------------------------------------------------------------------
__global__ __launch_bounds__(256) void init_hfrag(
    const float* __restrict__ h0, ushort_t* __restrict__ hf) {
    const int g = blockIdx.x, tid = threadIdx.x;
    const int bat0 = (g < 2) ? 7 * g : 14 + 6 * (g - 2);
    const int cnt  = (g < 2) ? 7 : 6;
    ushort_t* og = hf + (size_t)g * 8192;
    for (int i = tid; i < 8192; i += 256) {
        int jj = i & 7, cl = (i >> 3) & 31, ks = (i >> 8) & 15, hl = i >> 12;
        int m = cl & 7, oct = cl >> 3;
        int j = ks * 32 + oct * 8 + jj;
        float x = 0.0f;
        if (m < cnt) x = h0[(size_t)(bat0 + m) * H_ + j];
        ushort_t hi = bf16_rne(x);
        og[i] = hl ? bf16_rne(x - bf16_tof(hi)) : hi;
    }
}

// ---------------------------------------------------------------------------
// Fused 2-layer persistent LSTM scan, software-pipelined: at super-step s,
// layer0 computes t=s (s<T), layer1 computes t=s-1 (s>=1). 513 super-steps.
// 8 groups x 32 blocks; block (g,mB) owns components j0=16*mB..j0+15 of BOTH
// layers' h, all 4 gates. W_hh0/W_hh1 split-bf16 in regs (256 VGPRs);
// W_ih1 hi in regs (64), lo manually spilled to LDS (64 KB).
// h exchanged as split-bf16 A-frags via relaxed agent atomics (L3-coherent,
// no acquire/release -> no L2 wb/inv storms). Per-wave flags: wave0 signals
// h0 published, wave1 signals h1; consumers poll 64 flags (2/block).
// ---------------------------------------------------------------------------
__global__ __launch_bounds__(256, 1) void lstm_fused(
    const float* __restrict__ xg,     // [T][B][NG] layer0 gates, bias included
    ushort_t* __restrict__ hf0A, ushort_t* __restrict__ hf0B,
    ushort_t* __restrict__ hf1A, ushort_t* __restrict__ hf1B,
    const float* __restrict__ c0,     // [2][B][H]
    const float* __restrict__ W_hh0,  // [NG][H]
    const float* __restrict__ W_hh1,  // [NG][H]
    const float* __restrict__ W_ih1,  // [NG][H]
    const float* __restrict__ b1,     // [NG]
    float* __restrict__ hplain,       // [B][H] final layer-1 h
    int* __restrict__ flags) {        // NBLK*FLS ints, zeroed
    __shared__ ushort_t hfL0[16384];          // 32 KB expanded h0 A-frags
    __shared__ ushort_t hfL1[16384];          // 32 KB expanded h1 A-frags
    __shared__ float d0[4 * 4 * 8 * 16];      // 8 KB layer0 partials
    __shared__ float d1[4 * 4 * 8 * 16];      // 8 KB layer1 partials
    __shared__ short8 wlo[4 * 4 * 4 * 64];    // 64 KB W_ih1 lo B-frags
    const int tid = threadIdx.x, bid = blockIdx.x;
    const int g = bid >> 5, mB = bid & 31;
    const int j0 = mB * 16;
    const int bat0 = (g < 2) ? 7 * g : 14 + 6 * (g - 2);
    const int cnt  = (g < 2) ? 7 : 6;
    const int w = tid >> 6, L = tid & 63;

    // zero pad lanes (m>=8) of both frag buffers
    {
        ull_t* u0 = (ull_t*)hfL0;
        ull_t* u1 = (ull_t*)hfL1;
        for (int i = tid; i < 4096; i += 256)
            if ((((i >> 1) & 63) & 15) >= 8) { u0[i] = 0ULL; u1[i] = 0ULL; }
    }

    // ---- one-time W preload ----
    short8 Bhh0h[4][4], Bhh0l[4][4], Bhh1h[4][4], Bhh1l[4][4], Bih1h[4][4];
    {
        const int n = L & 15, oct = L >> 4;
#pragma unroll
        for (int q = 0; q < 4; ++q) {
            const size_t row = (size_t)(q * H_ + j0 + n) * H_;
#pragma unroll
            for (int kk = 0; kk < 4; ++kk) {
                int kbase = (w * 4 + kk) * 32 + oct * 8;
                // W_hh0
                {
                    float4 f0 = *(const float4*)(W_hh0 + row + kbase);
                    float4 f1 = *(const float4*)(W_hh0 + row + kbase + 4);
                    float xs[8] = {f0.x, f0.y, f0.z, f0.w, f1.x, f1.y, f1.z, f1.w};
                    union { ushort_t s[8]; short8 v; } uh, ul;
#pragma unroll
                    for (int e = 0; e < 8; ++e) {
                        ushort_t hi = bf16_rne(xs[e]);
                        uh.s[e] = hi; ul.s[e] = bf16_rne(xs[e] - bf16_tof(hi));
                    }
                    Bhh0h[q][kk] = uh.v; Bhh0l[q][kk] = ul.v;
                }
                // W_hh1
                {
                    float4 f0 = *(const float4*)(W_hh1 + row + kbase);
                    float4 f1 = *(const float4*)(W_hh1 + row + kbase + 4);
                    float xs[8] = {f0.x, f0.y, f0.z, f0.w, f1.x, f1.y, f1.z, f1.w};
                    union { ushort_t s[8]; short8 v; } uh, ul;
#pragma unroll
                    for (int e = 0; e < 8; ++e) {
                        ushort_t hi = bf16_rne(xs[e]);
                        uh.s[e] = hi; ul.s[e] = bf16_rne(xs[e] - bf16_tof(hi));
                    }
                    Bhh1h[q][kk] = uh.v; Bhh1l[q][kk] = ul.v;
                }
                // W_ih1: hi -> regs, lo -> LDS
                {
                    float4 f0 = *(const float4*)(W_ih1 + row + kbase);
                    float4 f1 = *(const float4*)(W_ih1 + row + kbase + 4);
                    float xs[8] = {f0.x, f0.y, f0.z, f0.w, f1.x, f1.y, f1.z, f1.w};
                    union { ushort_t s[8]; short8 v; } uh, ul;
#pragma unroll
                    for (int e = 0; e < 8; ++e) {
                        ushort_t hi = bf16_rne(xs[e]);
                        uh.s[e] = hi; ul.s[e] = bf16_rne(xs[e] - bf16_tof(hi));
                    }
                    Bih1h[q][kk] = uh.v;
                    wlo[((w * 4 + q) * 4 + kk) * 64 + L] = ul.v;
                }
            }
        }
    }

    // ---- gate-phase identities ----
    // wave0 (layer0): tid<56 -> (gm0=tid>>3, jlp0=(tid&7)*2)
    const int gm0 = tid >> 3, jlp0 = (tid & 7) * 2;
    const bool gok0 = (tid < 56) && (gm0 < cnt);
    const int gb0 = (bat0 + gm0 < B_) ? bat0 + gm0 : B_ - 1;
    float c0a = 0.f, c0b = 0.f;
    if (gok0) {
        c0a = c0[(size_t)gb0 * H_ + j0 + jlp0];
        c0b = c0[(size_t)gb0 * H_ + j0 + jlp0 + 1];
    }
    float2 xr[4];
    if (tid < 56) {
#pragma unroll
        for (int q = 0; q < 4; ++q)
            xr[q] = *(const float2*)(xg + (size_t)gb0 * NG_ + q * H_ + j0 + jlp0);
    }
    // wave1 (layer1): tid in [64,120) -> (gm1, jlp1)
    const int u1 = tid - 64;
    const int gm1 = u1 >> 3, jlp1 = (u1 & 7) * 2;
    const bool gok1 = (tid >= 64) && (tid < 120) && (gm1 < cnt);
    const int gb1 = (gok1 && bat0 + gm1 < B_) ? bat0 + gm1 : B_ - 1;
    float c1a = 0.f, c1b = 0.f;
    float2 b1r[4];
    if (gok1) {
        c1a = c0[(size_t)(B_ + gb1) * H_ + j0 + jlp1];
        c1b = c0[(size_t)(B_ + gb1) * H_ + j0 + jlp1 + 1];
#pragma unroll
        for (int q = 0; q < 4; ++q)
            b1r[q] = *(const float2*)(b1 + q * H_ + j0 + jlp1);
    }

    __syncthreads();   // wlo + pad-zero visible

    const short8* ap0 = (const short8*)hfL0;
    const short8* ap1 = (const short8*)hfL1;
    const f32x4 vzero = {0.f, 0.f, 0.f, 0.f};

    for (int s = 0; s <= T_; ++s) {
        const ushort_t* r0 = (s & 1) ? hf0A : hf0B;   // h0(s-1)
        ushort_t*       w0 = (s & 1) ? hf0B : hf0A;
        const ushort_t* r1 = (s & 1) ? hf1B : hf1A;   // h1(s-2)
        ushort_t*       w1 = (s & 1) ? hf1A : hf1B;

        // ---- stage both frag sets -> LDS expanded ----
        {
            const ull_t* s0 = (const ull_t*)(r0 + (size_t)g * 8192);
            const ull_t* s1 = (const ull_t*)(r1 + (size_t)g * 8192);
            ull_t* l0 = (ull_t*)hfL0;
            ull_t* l1 = (ull_t*)hfL1;
#pragma unroll
            for (int i = 0; i < 8; ++i) {
                int u = tid + i * 256;
                ull_t v0 = __hip_atomic_load(s0 + u, __ATOMIC_RELAXED, __HIP_MEMORY_SCOPE_AGENT);
                ull_t v1 = __hip_atomic_load(s1 + u, __ATOMIC_RELAXED, __HIP_MEMORY_SCOPE_AGENT);
                int jjh = u & 1, cl = (u >> 1) & 31, ks = (u >> 6) & 15, hl = (u >> 10) & 1;
                int el = (cl & 7) + 16 * (cl >> 3);
                int di = ((hl * 16 + ks) * 64 + el) * 2 + jjh;
                l0[di] = v0;
                l1[di] = v1;
            }
        }
        __syncthreads();

        // ---- layer-0 MFMA (t0 = s) ----
        if (s < T_) {
            f32x4 acc[4];
#pragma unroll
            for (int q = 0; q < 4; ++q) acc[q] = vzero;
#pragma unroll
            for (int kk = 0; kk < 4; ++kk) {
                int ksp = w * 4 + kk;
                short8 Ahi = ap0[ksp * 64 + L];
                short8 Alo = ap0[1024 + ksp * 64 + L];
#pragma unroll
                for (int q = 0; q < 4; ++q) {
                    acc[q] = __builtin_amdgcn_mfma_f32_16x16x32_bf16(Ahi, Bhh0h[q][kk], acc[q], 0, 0, 0);
                    acc[q] = __builtin_amdgcn_mfma_f32_16x16x32_bf16(Alo, Bhh0h[q][kk], acc[q], 0, 0, 0);
                    acc[q] = __builtin_amdgcn_mfma_f32_16x16x32_bf16(Ahi, Bhh0l[q][kk], acc[q], 0, 0, 0);
                }
            }
#pragma unroll
            for (int q = 0; q < 4; ++q)
#pragma unroll
                for (int r = 0; r < 4; ++r) {
                    int m = (L >> 4) * 4 + r;
                    if (m < 8) d0[((w * 4 + q) * 8 + m) * 16 + (L & 15)] = acc[q][r];
                }
        }
        // ---- layer-1 MFMA (t1 = s-1): W_ih1@h0(s-1) + W_hh1@h1(s-2) ----
        if (s >= 1) {
            f32x4 acc[4];
#pragma unroll
            for (int q = 0; q < 4; ++q) acc[q] = vzero;
#pragma unroll
            for (int kk = 0; kk < 4; ++kk) {
                int ksp = w * 4 + kk;
                short8 A0h = ap0[ksp * 64 + L];
                short8 A0l = ap0[1024 + ksp * 64 + L];
                short8 A1h = ap1[ksp * 64 + L];
                short8 A1l = ap1[1024 + ksp * 64 + L];
#pragma unroll
                for (int q = 0; q < 4; ++q) {
                    short8 Wl = wlo[((w * 4 + q) * 4 + kk) * 64 + L];
                    acc[q] = __builtin_amdgcn_mfma_f32_16x16x32_bf16(A0h, Bih1h[q][kk], acc[q], 0, 0, 0);
                    acc[q] = __builtin_amdgcn_mfma_f32_16x16x32_bf16(A0l, Bih1h[q][kk], acc[q], 0, 0, 0);
                    acc[q] = __builtin_amdgcn_mfma_f32_16x16x32_bf16(A0h, Wl, acc[q], 0, 0, 0);
                    acc[q] = __builtin_amdgcn_mfma_f32_16x16x32_bf16(A1h, Bhh1h[q][kk], acc[q], 0, 0, 0);
                    acc[q] = __builtin_amdgcn_mfma_f32_16x16x32_bf16(A1l, Bhh1h[q][kk], acc[q], 0, 0, 0);
                    acc[q] = __builtin_amdgcn_mfma_f32_16x16x32_bf16(A1h, Bhh1l[q][kk], acc[q], 0, 0, 0);
                }
            }
#pragma unroll
            for (int q = 0; q < 4; ++q)
#pragma unroll
                for (int r = 0; r < 4; ++r) {
                    int m = (L >> 4) * 4 + r;
                    if (m < 8) d1[((w * 4 + q) * 8 + m) * 16 + (L & 15)] = acc[q][r];
                }
        }
        __syncthreads();

        // ---- layer-0 gate phase (wave 0) + flagA ----
        if (s < T_) {
            if (gok0) {
                float ga[4], gb[4];
#pragma unroll
                for (int q = 0; q < 4; ++q) {
                    float sx = 0.f, sy = 0.f;
#pragma unroll
                    for (int ww = 0; ww < 4; ++ww) {
                        const float2 p = *(const float2*)&d0[((ww * 4 + q) * 8 + gm0) * 16 + jlp0];
                        sx += p.x; sy += p.y;
                    }
                    ga[q] = sx + xr[q].x;
                    gb[q] = sy + xr[q].y;
                }
                float cna = sigmf(ga[1]) * c0a + sigmf(ga[0]) * tanh_fast(ga[2]);
                float hna = sigmf(ga[3]) * tanh_fast(cna);
                float cnb = sigmf(gb[1]) * c0b + sigmf(gb[0]) * tanh_fast(gb[2]);
                float hnb = sigmf(gb[3]) * tanh_fast(cnb);
                c0a = cna; c0b = cnb;
                ushort_t hia = bf16_rne(hna), hib = bf16_rne(hnb);
                ushort_t loa = bf16_rne(hna - bf16_tof(hia));
                ushort_t lob = bf16_rne(hnb - bf16_tof(hib));
                int jA = j0 + jlp0;
                int cl = gm0 + 8 * ((jA >> 3) & 3);
                int ks = jA >> 5, jj = jA & 7;
                ushort_t* og = w0 + (size_t)g * 8192;
                unsigned hv = (unsigned)hia | ((unsigned)hib << 16);
                unsigned lv = (unsigned)loa | ((unsigned)lob << 16);
                __hip_atomic_store((unsigned*)(og + (ks * 256 + cl * 8 + jj)), hv,
                                   __ATOMIC_RELAXED, __HIP_MEMORY_SCOPE_AGENT);
                __hip_atomic_store((unsigned*)(og + (4096 + ks * 256 + cl * 8 + jj)), lv,
                                   __ATOMIC_RELAXED, __HIP_MEMORY_SCOPE_AGENT);
            }
        }
        if (tid == 0) {
            asm volatile("s_waitcnt vmcnt(0)" ::: "memory");
            __hip_atomic_store(flags + (size_t)bid * FLS + 0, s + 1,
                               __ATOMIC_RELAXED, __HIP_MEMORY_SCOPE_AGENT);
        }
        // prefetch next xg tile (after flagA so it doesn't delay the signal)
        if (tid < 56 && s + 1 < T_) {
#pragma unroll
            for (int q = 0; q < 4; ++q)
                xr[q] = *(const float2*)(xg + ((size_t)(s + 1) * B_ + gb0) * NG_ + q * H_ + j0 + jlp0);
        }

        // ---- layer-1 gate phase (wave 1) + flagB ----
        if (s >= 1 && gok1) {
            float ga[4], gb[4];
#pragma unroll
            for (int q = 0; q < 4; ++q) {
                float sx = 0.f, sy = 0.f;
#pragma unroll
                for (int ww = 0; ww < 4; ++ww) {
                    const float2 p = *(const float2*)&d1[((ww * 4 + q) * 8 + gm1) * 16 + jlp1];
                    sx += p.x; sy += p.y;
                }
                ga[q] = sx + b1r[q].x;
                gb[q] = sy + b1r[q].y;
            }
            float cna = sigmf(ga[1]) * c1a + sigmf(ga[0]) * tanh_fast(ga[2]);
            float hna = sigmf(ga[3]) * tanh_fast(cna);
            float cnb = sigmf(gb[1]) * c1b + sigmf(gb[0]) * tanh_fast(gb[2]);
            float hnb = sigmf(gb[3]) * tanh_fast(cnb);
            c1a = cna; c1b = cnb;
            ushort_t hia = bf16_rne(hna), hib = bf16_rne(hnb);
            ushort_t loa = bf16_rne(hna - bf16_tof(hia));
            ushort_t lob = bf16_rne(hnb - bf16_tof(hib));
            int jA = j0 + jlp1;
            int cl = gm1 + 8 * ((jA >> 3) & 3);
            int ks = jA >> 5, jj = jA & 7;
            ushort_t* og = w1 + (size_t)g * 8192;
            unsigned hv = (unsigned)hia | ((unsigned)hib << 16);
            unsigned lv = (unsigned)loa | ((unsigned)lob << 16);
            __hip_atomic_store((unsigned*)(og + (ks * 256 + cl * 8 + jj)), hv,
                               __ATOMIC_RELAXED, __HIP_MEMORY_SCOPE_AGENT);
            __hip_atomic_store((unsigned*)(og + (4096 + ks * 256 + cl * 8 + jj)), lv,
                               __ATOMIC_RELAXED, __HIP_MEMORY_SCOPE_AGENT);
            if (s == T_) *(float2*)(hplain + (size_t)gb1 * H_ + jA) = make_float2(hna, hnb);
        }
        if (tid == 64) {
            asm volatile("s_waitcnt vmcnt(0)" ::: "memory");
            __hip_atomic_store(flags + (size_t)bid * FLS + 1, s + 1,
                               __ATOMIC_RELAXED, __HIP_MEMORY_SCOPE_AGENT);
        }

        // ---- poll: wave 0 checks both flags of all 32 group blocks ----
        if (tid < 64) {
            const int tgt = s + 1;
            const int* f = flags + (size_t)(g * 32 + (tid & 31)) * FLS + (tid >> 5);
            for (;;) {
                int v = __hip_atomic_load(f, __ATOMIC_RELAXED, __HIP_MEMORY_SCOPE_AGENT);
                if (__all(v >= tgt)) break;
                __builtin_amdgcn_s_sleep(2);
            }
        }
        __syncthreads();
    }
}

// ---------------------------------------------------------------------------
// head: hT layout [b][H]
// ---------------------------------------------------------------------------
__global__ __launch_bounds__(512) void head(
    const float* __restrict__ hT, const float* __restrict__ lin1_W,
    const float* __restrict__ lin1_b, const float* __restrict__ lin2_W,
    const float* __restrict__ lin2_b, float* __restrict__ out) {
    __shared__ float zs[B_][10];
    int tid = threadIdx.x;
    if (tid < B_ * 10) {
        int b = tid / 10, u = tid % 10;
        float acc = lin1_b[u];
        for (int j = 0; j < H_; j += 4) {
            float4 hv = *(const float4*)&hT[(size_t)b * H_ + j];
            float4 wv = *(const float4*)&lin1_W[(size_t)u * H_ + j];
            acc = fmaf(hv.x, wv.x, acc);
            acc = fmaf(hv.y, wv.y, acc);
            acc = fmaf(hv.z, wv.z, acc);
            acc = fmaf(hv.w, wv.w, acc);
        }
        zs[b][u] = tanh_fast(acc);
    }
    __syncthreads();
    if (tid < B_ * 2) {
        int b = tid >> 1, o = tid & 1;
        float acc = lin2_b[o];
#pragma unroll
        for (int u = 0; u < 10; ++u)
            acc = fmaf(zs[b][u], lin2_W[o * 10 + u], acc);
        out[b * 2 + o] = acc;
    }
}

// ---------------------------------------------------------------------------
extern "C" void kernel_launch(void* const* d_in, const int* in_sizes, int n_in,
                              void* d_out, int out_size, void* d_ws, size_t ws_size,
                              hipStream_t stream) {
    const float* input  = (const float*)d_in[0];
    const float* pca_W  = (const float*)d_in[1];
    const float* pca_b  = (const float*)d_in[2];
    const float* W_ih0  = (const float*)d_in[3];
    const float* W_hh0  = (const float*)d_in[4];
    const float* b0     = (const float*)d_in[5];
    const float* W_ih1  = (const float*)d_in[6];
    const float* W_hh1  = (const float*)d_in[7];
    const float* b1     = (const float*)d_in[8];
    const float* h0     = (const float*)d_in[9];
    const float* c0     = (const float*)d_in[10];
    const float* lin1_W = (const float*)d_in[11];
    const float* lin1_b = (const float*)d_in[12];
    const float* lin2_W = (const float*)d_in[13];
    const float* lin2_b = (const float*)d_in[14];
    float* out = (float*)d_out;

    float* ws = (float*)d_ws;
    size_t off = 0;
    float* xg     = ws + off; off += (size_t)B_ * T_ * NG_;  // [T][B][NG]
    float* xbuf   = ws + off; off += (size_t)B_ * T_ * H_;
    float* hplain = ws + off; off += B_ * H_;
    ushort_t* hf0A = (ushort_t*)(ws + off); off += 32768;    // 8 x 8192 ushorts
    ushort_t* hf0B = (ushort_t*)(ws + off); off += 32768;
    ushort_t* hf1A = (ushort_t*)(ws + off); off += 32768;
    ushort_t* hf1B = (ushort_t*)(ws + off); off += 32768;
    int* flg = (int*)(ws + off); off += NBLK * FLS;

    const int M = B_ * T_;  // 25600

    // flags must start at 0 (ws re-poisoned 0xAA before every timed launch)
    hipMemsetAsync(flg, 0, NBLK * FLS * sizeof(int), stream);

    // initial states -> frag buffers (read at s=0 / s=1 respectively)
    init_hfrag<<<8, 256, 0, stream>>>(h0, hf0B);
    init_hfrag<<<8, 256, 0, stream>>>(h0 + B_ * H_, hf1B);

    // 1. pca: xbuf = input @ pca_W^T + pca_b   (row-major [B*T][H])
    {
        dim3 g(H_ / 128, M / 128);
        gemm_bias_mfma<<<g, 256, 0, stream>>>(input, pca_W, pca_b, xbuf, M, H_, I_, 0);
    }
    // 2. xg0 = xbuf @ W_ih0^T + b0, stored [T][B][NG]
    {
        dim3 g(NG_ / 128, M / 128);
        gemm_bias_mfma<<<g, 256, 0, stream>>>(xbuf, W_ih0, b0, xg, M, NG_, H_, 1);
    }
    // 3. fused 2-layer pipelined scan
    lstm_fused<<<NBLK, 256, 0, stream>>>(xg, hf0A, hf0B, hf1A, hf1B, c0,
                                         W_hh0, W_hh1, W_ih1, b1, hplain, flg);
    // 4. head
    head<<<1, 512, 0, stream>>>(hplain, lin1_W, lin1_b, lin2_W, lin2_b, out);
}